// Round 9
// baseline (301.073 us; speedup 1.0000x reference)
//
#include <hip/hip_runtime.h>
#include <hip/hip_bf16.h>
#include <math.h>

#define EPS_  1e-8f
#define LNEPS 1e-5f

typedef __attribute__((ext_vector_type(8))) short   short8;
typedef __attribute__((ext_vector_type(8))) __bf16  bf16x8;
typedef __attribute__((ext_vector_type(4))) float   f32x4;
typedef unsigned short ushort_t;

__device__ __forceinline__ float bf2f(unsigned int u) { return __uint_as_float(u << 16); }
__device__ __forceinline__ unsigned short f2bf(float f) {
    unsigned int u = __float_as_uint(f);
    u += 0x7fff + ((u >> 16) & 1);
    return (unsigned short)(u >> 16);
}
__device__ __forceinline__ f32x4 mfma_bf16(short8 a, short8 b, f32x4 c) {
    union U { short8 s; bf16x8 b; };
    U ua, ub; ua.s = a; ub.s = b;
    return __builtin_amdgcn_mfma_f32_16x16x32_bf16(ua.b, ub.b, c, 0, 0, 0);
}
__device__ __forceinline__ float wred_sum(float v) {
#pragma unroll
    for (int off = 32; off > 0; off >>= 1) v += __shfl_xor(v, off);
    return v;
}

// -------- prepack Wk/Wv -> Wt[n][k] bf16 (k pre-scaled 0.125) --------
__global__ __launch_bounds__(256) void prepack_w_kernel(const float* __restrict__ Wk,
                                                        const float* __restrict__ Wv,
                                                        ushort_t* __restrict__ Wt) {
    int n = blockIdx.x;
    int k = threadIdx.x;
    float v = (n < 256) ? Wk[(size_t)k * 256 + n] * 0.125f : Wv[(size_t)k * 256 + (n - 256)];
    Wt[(size_t)n * 256 + k] = f2bf(v);
}

// -------- prepack Wt -> Wtp: MFMA B-fragments for kvproj --------
__global__ __launch_bounds__(256) void prepack_wtp_kernel(const ushort_t* __restrict__ Wt,
                                                          ushort_t* __restrict__ Wtp) {
    int bs = blockIdx.x;              // cg*8+s, 0..63
    int ni = threadIdx.x >> 6, l = threadIdx.x & 63;
    int cg = bs >> 3, s = bs & 7;
    int n  = cg * 64 + ni * 16 + (l & 15);
    int k0 = s * 32 + (l >> 4) * 8;
    short8 v = *(const short8*)(Wt + (size_t)n * 256 + k0);
    *(short8*)(Wtp + ((size_t)bs * 4 + ni) * 512 + l * 8) = v;
}

// -------- prepack slot-chain weights into MFMA B-fragments --------
// m=0: w_ih [768n][256k]; m=1: w_hh [768n][256k]; m=2: w1 [256k][512n]; m=3: w2 [512k][256n]
__global__ __launch_bounds__(256) void prepack_frags_kernel(const float* __restrict__ w_ih,
                                                            const float* __restrict__ w_hh,
                                                            const float* __restrict__ w1,
                                                            const float* __restrict__ w2,
                                                            ushort_t* __restrict__ ihfr,
                                                            ushort_t* __restrict__ hhfr,
                                                            ushort_t* __restrict__ w1fr,
                                                            ushort_t* __restrict__ w2fr) {
    int m = blockIdx.y, bs = blockIdx.x;
    int ni = threadIdx.x >> 6, l = threadIdx.x & 63;
    int nloc = ni * 16 + (l & 15);
    int kb = (l >> 4) * 8;
    short8 v;
    if (m <= 1) {                     // N=768, K=256, S=8: bs = cg*8+s, cg<12
        if (bs >= 96) return;
        int cg = bs >> 3, s = bs & 7;
        const float* src = m ? w_hh : w_ih;
        int n = cg * 64 + nloc, k0 = s * 32 + kb;
#pragma unroll
        for (int j = 0; j < 8; j++) v[j] = (short)f2bf(src[(size_t)n * 256 + k0 + j]);
        ushort_t* dst = m ? hhfr : ihfr;
        *(short8*)&dst[((size_t)bs * 4 + ni) * 512 + l * 8] = v;
    } else if (m == 2) {              // N=512, K=256, S=8: bs = cg*8+s, cg<8
        if (bs >= 64) return;
        int cg = bs >> 3, s = bs & 7;
        int n = cg * 64 + nloc, k0 = s * 32 + kb;
#pragma unroll
        for (int j = 0; j < 8; j++) v[j] = (short)f2bf(w1[(size_t)(k0 + j) * 512 + n]);
        *(short8*)&w1fr[((size_t)bs * 4 + ni) * 512 + l * 8] = v;
    } else {                          // N=256, K=512, S=16: bs = cg*16+s, cg<4
        if (bs >= 64) return;
        int cg = bs >> 4, s = bs & 15;
        int n = cg * 64 + nloc, k0 = s * 32 + kb;
#pragma unroll
        for (int j = 0; j < 8; j++) v[j] = (short)f2bf(w2[(size_t)(k0 + j) * 256 + n]);
        *(short8*)&w2fr[((size_t)bs * 4 + ni) * 512 + l * 8] = v;
    }
}

// -------- KV projection v5: coalesced A-stage, B-stream, LDS-staged coalesced epilogue ----
__global__ __launch_bounds__(512, 4) void kvproj_mfma_kernel(const float* __restrict__ in,
                                                             const float* __restrict__ g,
                                                             const float* __restrict__ bb,
                                                             const ushort_t* __restrict__ Wtp,
                                                             ushort_t* __restrict__ kvout) {
    __shared__ __align__(16) ushort_t As[64 * 264];  // MFMA phase: stride 256; epilogue: 264
    const int tid = threadIdx.x;
    const int wv = tid >> 6, l = tid & 63;
    const int kc = l >> 4, lr = l & 15;
    const int m0 = blockIdx.x * 64;

    float4 g4 = *(const float4*)(g + l * 4);
    float4 b4 = *(const float4*)(bb + l * 4);
    float4 xv[8];
#pragma unroll
    for (int i = 0; i < 8; i++)
        xv[i] = *(const float4*)(in + (size_t)(m0 + i * 8 + wv) * 256 + l * 4);
#pragma unroll
    for (int i = 0; i < 8; i++) {
        float s1 = xv[i].x + xv[i].y + xv[i].z + xv[i].w;
        float s2 = xv[i].x * xv[i].x + xv[i].y * xv[i].y + xv[i].z * xv[i].z + xv[i].w * xv[i].w;
        s1 = wred_sum(s1);
        s2 = wred_sum(s2);
        float m = s1 * (1.0f / 256.0f);
        float r = rsqrtf(s2 * (1.0f / 256.0f) - m * m + LNEPS);
        unsigned int p0 = f2bf((xv[i].x - m) * r * g4.x + b4.x);
        unsigned int p1 = f2bf((xv[i].y - m) * r * g4.y + b4.y);
        unsigned int p2 = f2bf((xv[i].z - m) * r * g4.z + b4.z);
        unsigned int p3 = f2bf((xv[i].w - m) * r * g4.w + b4.w);
        uint2 pk = {p0 | (p1 << 16), p2 | (p3 << 16)};
        int row = i * 8 + wv;
        *(uint2*)&As[row * 256 + (((l >> 1) ^ (row & 7)) * 8) + (l & 1) * 4] = pk;
    }
    __syncthreads();

    f32x4 zero = {0.f, 0.f, 0.f, 0.f};
    f32x4 acc[4][4];
#pragma unroll
    for (int i = 0; i < 4; i++)
#pragma unroll
        for (int jj = 0; jj < 4; jj++) acc[i][jj] = zero;

#pragma unroll
    for (int s = 0; s < 8; s++) {
        short8 bfr[4];
        const ushort_t* wpb = Wtp + ((size_t)(wv * 8 + s) * 4) * 512 + l * 8;
#pragma unroll
        for (int ni = 0; ni < 4; ni++) bfr[ni] = *(const short8*)(wpb + ni * 512);
        short8 af[4];
#pragma unroll
        for (int mi = 0; mi < 4; mi++) {
            int r2 = lr + mi * 16;
            int c = s * 4 + kc;
            af[mi] = *(const short8*)&As[r2 * 256 + ((c ^ (r2 & 7)) * 8)];
        }
#pragma unroll
        for (int mi = 0; mi < 4; mi++)
#pragma unroll
            for (int ni = 0; ni < 4; ni++)
                acc[mi][ni] = mfma_bf16(af[mi], bfr[ni], acc[mi][ni]);
    }
    // ---- epilogue: stage halves in LDS, store coalesced rows ----
    __syncthreads();
#pragma unroll
    for (int half = 0; half < 2; half++) {
        if ((wv >> 2) == half) {
            int cw = (wv & 3) * 64;
#pragma unroll
            for (int mi = 0; mi < 4; mi++)
#pragma unroll
                for (int ni = 0; ni < 4; ni++)
#pragma unroll
                    for (int r = 0; r < 4; r++)
                        As[(mi * 16 + kc * 4 + r) * 264 + cw + ni * 16 + lr] =
                            f2bf(acc[mi][ni][r]);
        }
        __syncthreads();
        {
            int row = tid >> 3, seg = tid & 7;
            const ushort_t* srcp = &As[row * 264 + seg * 32];
            ushort_t* dstp = kvout + (size_t)(m0 + row) * 512 + half * 256 + seg * 32;
#pragma unroll
            for (int j = 0; j < 4; j++)
                *(uint4*)(dstp + j * 8) = *(const uint4*)(srcp + j * 8);
        }
        __syncthreads();
    }
}

// -------- slot LN + q projection. grid 512 x 256 --------
__global__ __launch_bounds__(256) void qproj_kernel(const float* __restrict__ slots,
                                                    const float* __restrict__ g,
                                                    const float* __restrict__ bvec,
                                                    const float* __restrict__ Wq,
                                                    float* __restrict__ qp) {
    int row = blockIdx.x;
    int tid = threadIdx.x;
    __shared__ float s_s[256];
    __shared__ float red[8];
    float x = slots[(size_t)row * 256 + tid];
    float s1 = wred_sum(x);
    float s2 = wred_sum(x * x);
    if ((tid & 63) == 0) { red[tid >> 6] = s1; red[4 + (tid >> 6)] = s2; }
    __syncthreads();
    float m  = (red[0] + red[1] + red[2] + red[3]) * (1.0f / 256.0f);
    float e2 = (red[4] + red[5] + red[6] + red[7]) * (1.0f / 256.0f);
    float rst = rsqrtf(e2 - m * m + LNEPS);
    s_s[tid] = (x - m) * rst * g[tid] + bvec[tid];
    __syncthreads();
    float acc = 0.f;
#pragma unroll 4
    for (int d = 0; d < 256; d++) acc += s_s[d] * Wq[(size_t)d * 256 + tid];
    int b = row >> 3, q = row & 7;
    qp[((size_t)(b * 4 + (tid >> 6)) * 8 + q) * 64 + (tid & 63)] = acc;
}

// -------- fused attention v4 (unchanged from round 7) --------
__global__ __launch_bounds__(256) void attn_fused_kernel(const ushort_t* __restrict__ kv,
                                                         const float* __restrict__ qp,
                                                         float* __restrict__ Upart,
                                                         float* __restrict__ Cpart,
                                                         float* __restrict__ vis,
                                                         int write_vis) {
    int b = blockIdx.y;
    int chunk = blockIdx.x;
    int tid = threadIdx.x;
    __shared__ __align__(16) ushort_t qfrag[16 * 512];
    __shared__ float att[128][32];
    __shared__ float ubuf[2][2048];
    __shared__ float cred[8][32];

    {
        const float* qb_ = qp + (size_t)b * 2048;
#pragma unroll
        for (int snt = 0; snt < 16; snt++) {
            int s = snt >> 1, nt = snt & 1;
#pragma unroll
            for (int rep = 0; rep < 2; rep++) {
                int idx = tid + rep * 256;
                int k  = s * 32 + ((idx >> 7) << 3) + (idx & 7);
                int hq = nt * 16 + ((idx >> 3) & 15);
                float v = ((k >> 6) == (hq >> 3))
                              ? qb_[(hq >> 3) * 512 + (hq & 7) * 64 + (k & 63)] : 0.f;
                qfrag[snt * 512 + idx] = f2bf(v);
            }
        }
    }
    __syncthreads();

    const int w = tid >> 6, l = tid & 63;
    const int lr = l & 15, kc8 = (l >> 4) * 8;

    short8 qb2[2][8];
#pragma unroll
    for (int s = 0; s < 8; s++) {
        qb2[0][s] = *(const short8*)&qfrag[(s * 2 + 0) * 512 + l * 8];
        qb2[1][s] = *(const short8*)&qfrag[(s * 2 + 1) * 512 + l * 8];
    }
    f32x4 zero = {0.f, 0.f, 0.f, 0.f};
#pragma unroll
    for (int mi_loc = 0; mi_loc < 2; mi_loc++) {
        int mi = w * 2 + mi_loc;
        f32x4 a0 = zero, a1 = zero;
        const ushort_t* abase = kv + (size_t)(b * 1024 + chunk * 128 + mi * 16 + lr) * 512 + kc8;
#pragma unroll
        for (int s = 0; s < 8; s++) {
            short8 af = *(const short8*)(abase + s * 32);
            a0 = mfma_bf16(af, qb2[0][s], a0);
            a1 = mfma_bf16(af, qb2[1][s], a1);
        }
        int row0 = mi * 16 + (l >> 4) * 4;
#pragma unroll
        for (int r = 0; r < 4; r++) {
            att[row0 + r][lr]      = a0[r];
            att[row0 + r][16 + lr] = a1[r];
        }
    }
    __syncthreads();

    {
        int token = tid >> 1, half = tid & 1;
        float v[16];
        float mx = -3.4e38f;
#pragma unroll
        for (int j = 0; j < 16; j++) { v[j] = att[token][half * 16 + j]; mx = fmaxf(mx, v[j]); }
        mx = fmaxf(mx, __shfl_xor(mx, 1));
        float sm = 0.f;
#pragma unroll
        for (int j = 0; j < 16; j++) { v[j] = __expf(v[j] - mx); sm += v[j]; }
        sm += __shfl_xor(sm, 1);
        float inv = 1.0f / sm;
#pragma unroll
        for (int j = 0; j < 16; j++) { v[j] *= inv; att[token][half * 16 + j] = v[j] + EPS_; }
        if (write_vis) {
#pragma unroll
            for (int q = 0; q < 8; q++) {
                float pv = v[q] + v[q + 8];
                float pf = pv + __shfl_xor(pv, 1);
                if (half == 0) vis[(size_t)(b * 8 + q) * 1024 + chunk * 128 + token] = pf;
            }
        }
    }
    __syncthreads();

    {
        int hq2 = tid & 31, grp = tid >> 5;
        float s = 0.f;
#pragma unroll
        for (int i = 0; i < 16; i++) s += att[grp * 16 + i][hq2];
        cred[grp][hq2] = s;
    }
    __syncthreads();
    if (tid < 32) {
        float s = 0.f;
#pragma unroll
        for (int g2 = 0; g2 < 8; g2++) s += cred[g2][tid];
        Cpart[(size_t)(b * 8 + chunk) * 32 + tid] = s;
    }

    const int h_u = l >> 4, d4 = l & 15;
    const int uo = h_u * 64 + d4 * 4;
    float U[8][4];
#pragma unroll
    for (int q = 0; q < 8; q++)
#pragma unroll
        for (int d = 0; d < 4; d++) U[q][d] = 0.f;
    const ushort_t* vbase = kv + (size_t)(b * 1024 + chunk * 128 + w * 32) * 512 + 256 + uo;
    for (int i = 0; i < 32; ++i) {
        uint2 vp = *(const uint2*)(vbase + (size_t)i * 512);
        float v0 = bf2f(vp.x & 0xffffu), v1 = bf2f(vp.x >> 16);
        float v2 = bf2f(vp.y & 0xffffu), v3 = bf2f(vp.y >> 16);
        const float* arow = &att[w * 32 + i][h_u * 8];
        float4 a01 = *(const float4*)(arow);
        float4 a23 = *(const float4*)(arow + 4);
        float aq[8] = {a01.x, a01.y, a01.z, a01.w, a23.x, a23.y, a23.z, a23.w};
#pragma unroll
        for (int q = 0; q < 8; q++) {
            U[q][0] += aq[q] * v0; U[q][1] += aq[q] * v1;
            U[q][2] += aq[q] * v2; U[q][3] += aq[q] * v3;
        }
    }
    if (w & 1) {
        float* dst = ubuf[w >> 1];
#pragma unroll
        for (int q = 0; q < 8; q++) {
            float4 uq = {U[q][0], U[q][1], U[q][2], U[q][3]};
            *(float4*)(dst + q * 256 + uo) = uq;
        }
    }
    __syncthreads();
    if (!(w & 1)) {
        const float* src = ubuf[w >> 1];
#pragma unroll
        for (int q = 0; q < 8; q++) {
            float4 uq = *(const float4*)(src + q * 256 + uo);
            U[q][0] += uq.x; U[q][1] += uq.y; U[q][2] += uq.z; U[q][3] += uq.w;
        }
    }
    __syncthreads();
    if (w == 2) {
        float* dst = ubuf[0];
#pragma unroll
        for (int q = 0; q < 8; q++) {
            float4 uq = {U[q][0], U[q][1], U[q][2], U[q][3]};
            *(float4*)(dst + q * 256 + uo) = uq;
        }
    }
    __syncthreads();
    if (w == 0) {
        const float* src = ubuf[0];
        float* up = Upart + (size_t)(b * 8 + chunk) * 2048 + uo;
#pragma unroll
        for (int q = 0; q < 8; q++) {
            float4 uq = *(const float4*)(src + q * 256 + uo);
            float4 o = {U[q][0] + uq.x, U[q][1] + uq.y, U[q][2] + uq.z, U[q][3] + uq.w};
            *(float4*)(up + q * 256) = o;
        }
    }
}

// -------- updates_final: reduce partials, normalize, emit bf16 A-matrices --------
// grid 64 (b) x 256
__global__ __launch_bounds__(256) void updates_final_kernel(const float* __restrict__ Upart,
                                                            const float* __restrict__ Cpart,
                                                            const float* __restrict__ slotsIn,
                                                            ushort_t* __restrict__ U_bf,
                                                            ushort_t* __restrict__ H_bf) {
    int b = blockIdx.x, c = threadIdx.x, h = c >> 6;
#pragma unroll
    for (int q = 0; q < 8; q++) {
        float C = 0.f, s = 0.f;
#pragma unroll
        for (int p = 0; p < 8; p++) {
            C += Cpart[(size_t)(b * 8 + p) * 32 + h * 8 + q];
            s += Upart[(size_t)(b * 8 + p) * 2048 + q * 256 + c];
        }
        int row = b * 8 + q;
        U_bf[(size_t)row * 256 + c] = f2bf(s / C);
        H_bf[(size_t)row * 256 + c] = f2bf(slotsIn[(size_t)row * 256 + c]);
    }
}

// -------- GRU GEMM: gg[512][1536] = [U_bf|H_bf](64-row tiles) @ w^T + bias ----
// grid (8 mtile, 3 ntile, 2 z) x 256
__global__ __launch_bounds__(256) void gru_gemm_kernel(const ushort_t* __restrict__ U_bf,
                                                       const ushort_t* __restrict__ H_bf,
                                                       const ushort_t* __restrict__ ihfr,
                                                       const ushort_t* __restrict__ hhfr,
                                                       const float* __restrict__ b_ih,
                                                       const float* __restrict__ b_hh,
                                                       float* __restrict__ gg) {
    __shared__ __align__(16) ushort_t As[64 * 256];
    const int t = threadIdx.x;
    const int mtile = blockIdx.x, ntile = blockIdx.y, z = blockIdx.z;
    const ushort_t* Abf = z ? H_bf : U_bf;
    const ushort_t* fr  = z ? hhfr : ihfr;
    const float* bias   = z ? b_hh : b_ih;
    {
        int row = t >> 2, seg = t & 3;
        const ushort_t* src = Abf + (size_t)(mtile * 64 + row) * 256 + seg * 64;
#pragma unroll
        for (int i = 0; i < 8; i++) {
            uint4 v = *(const uint4*)(src + i * 8);
            int c = seg * 8 + i;
            *(uint4*)&As[row * 256 + ((c ^ (row & 7)) * 8)] = v;
        }
    }
    __syncthreads();
    const int wv = t >> 6, l = t & 63, kc = l >> 4, lr = l & 15;
    f32x4 zero = {0.f, 0.f, 0.f, 0.f};
    f32x4 acc[4][4];
#pragma unroll
    for (int i = 0; i < 4; i++)
#pragma unroll
        for (int jj = 0; jj < 4; jj++) acc[i][jj] = zero;
    const int cg = ntile * 4 + wv;
#pragma unroll
    for (int s = 0; s < 8; s++) {
        short8 bfr[4];
        const ushort_t* fp = fr + ((size_t)(cg * 8 + s) * 4) * 512 + l * 8;
#pragma unroll
        for (int ni = 0; ni < 4; ni++) bfr[ni] = *(const short8*)(fp + ni * 512);
        short8 af[4];
#pragma unroll
        for (int mi = 0; mi < 4; mi++) {
            int r2 = lr + mi * 16;
            int c = s * 4 + kc;
            af[mi] = *(const short8*)&As[r2 * 256 + ((c ^ (r2 & 7)) * 8)];
        }
#pragma unroll
        for (int mi = 0; mi < 4; mi++)
#pragma unroll
            for (int ni = 0; ni < 4; ni++)
                acc[mi][ni] = mfma_bf16(af[mi], bfr[ni], acc[mi][ni]);
    }
#pragma unroll
    for (int mi = 0; mi < 4; mi++)
#pragma unroll
        for (int ni = 0; ni < 4; ni++)
#pragma unroll
            for (int r = 0; r < 4; r++) {
                int rowg = mtile * 64 + mi * 16 + kc * 4 + r;
                int ng = ntile * 256 + wv * 64 + ni * 16 + lr;
                gg[(size_t)rowg * 1536 + z * 768 + ng] = acc[mi][ni][r] + bias[ng];
            }
}

// -------- gates + LN(mlp): SB f32, M_bf bf16. grid 512 x 256 --------
__global__ __launch_bounds__(256) void gate_ln_kernel(const float* __restrict__ gg,
                                                      const float* __restrict__ slotsIn,
                                                      const float* __restrict__ ln_g,
                                                      const float* __restrict__ ln_b,
                                                      float* __restrict__ SB,
                                                      ushort_t* __restrict__ M_bf) {
    int row = blockIdx.x, c = threadIdx.x;
    __shared__ float red[8];
    const float* gr = gg + (size_t)row * 1536;
    float xr = gr[c], xz = gr[256 + c], xn = gr[512 + c];
    float hr = gr[768 + c], hz = gr[1024 + c], hn = gr[1280 + c];
    float hp = slotsIn[(size_t)row * 256 + c];
    float rg = 1.f / (1.f + __expf(-(xr + hr)));
    float z  = 1.f / (1.f + __expf(-(xz + hz)));
    float nn = tanhf(xn + rg * hn);
    float sb = (1.f - z) * nn + z * hp;
    SB[(size_t)row * 256 + c] = sb;
    float s1 = wred_sum(sb), s2 = wred_sum(sb * sb);
    if ((c & 63) == 0) { red[c >> 6] = s1; red[4 + (c >> 6)] = s2; }
    __syncthreads();
    float m  = (red[0] + red[1] + red[2] + red[3]) * (1.0f / 256.0f);
    float e2 = (red[4] + red[5] + red[6] + red[7]) * (1.0f / 256.0f);
    float rst = rsqrtf(e2 - m * m + LNEPS);
    M_bf[(size_t)row * 256 + c] = f2bf((sb - m) * rst * ln_g[c] + ln_b[c]);
}

// -------- MLP1 GEMM: hid_bf[512][512] = relu(M_bf @ w1 + b1). grid (8, 2) x 256 ----
__global__ __launch_bounds__(256) void mlp1_gemm_kernel(const ushort_t* __restrict__ M_bf,
                                                        const ushort_t* __restrict__ w1fr,
                                                        const float* __restrict__ b1,
                                                        ushort_t* __restrict__ hid_bf) {
    __shared__ __align__(16) ushort_t As[64 * 256];
    const int t = threadIdx.x;
    const int mtile = blockIdx.x, ntile = blockIdx.y;
    {
        int row = t >> 2, seg = t & 3;
        const ushort_t* src = M_bf + (size_t)(mtile * 64 + row) * 256 + seg * 64;
#pragma unroll
        for (int i = 0; i < 8; i++) {
            uint4 v = *(const uint4*)(src + i * 8);
            int c = seg * 8 + i;
            *(uint4*)&As[row * 256 + ((c ^ (row & 7)) * 8)] = v;
        }
    }
    __syncthreads();
    const int wv = t >> 6, l = t & 63, kc = l >> 4, lr = l & 15;
    f32x4 zero = {0.f, 0.f, 0.f, 0.f};
    f32x4 acc[4][4];
#pragma unroll
    for (int i = 0; i < 4; i++)
#pragma unroll
        for (int jj = 0; jj < 4; jj++) acc[i][jj] = zero;
    const int cg = ntile * 4 + wv;
#pragma unroll
    for (int s = 0; s < 8; s++) {
        short8 bfr[4];
        const ushort_t* fp = w1fr + ((size_t)(cg * 8 + s) * 4) * 512 + l * 8;
#pragma unroll
        for (int ni = 0; ni < 4; ni++) bfr[ni] = *(const short8*)(fp + ni * 512);
        short8 af[4];
#pragma unroll
        for (int mi = 0; mi < 4; mi++) {
            int r2 = lr + mi * 16;
            int c = s * 4 + kc;
            af[mi] = *(const short8*)&As[r2 * 256 + ((c ^ (r2 & 7)) * 8)];
        }
#pragma unroll
        for (int mi = 0; mi < 4; mi++)
#pragma unroll
            for (int ni = 0; ni < 4; ni++)
                acc[mi][ni] = mfma_bf16(af[mi], bfr[ni], acc[mi][ni]);
    }
#pragma unroll
    for (int mi = 0; mi < 4; mi++)
#pragma unroll
        for (int ni = 0; ni < 4; ni++)
#pragma unroll
            for (int r = 0; r < 4; r++) {
                int rowg = mtile * 64 + mi * 16 + kc * 4 + r;
                int ng = ntile * 256 + wv * 64 + ni * 16 + lr;
                hid_bf[(size_t)rowg * 512 + ng] = f2bf(fmaxf(acc[mi][ni][r] + b1[ng], 0.f));
            }
}

// -------- MLP2 GEMM: out[512][256] = hid_bf @ w2 + b2 + SB. grid (8) x 256, K=512 ----
__global__ __launch_bounds__(256) void mlp2_gemm_kernel(const ushort_t* __restrict__ hid_bf,
                                                        const ushort_t* __restrict__ w2fr,
                                                        const float* __restrict__ b2,
                                                        const float* __restrict__ SB,
                                                        float* __restrict__ outS) {
    __shared__ __align__(16) ushort_t As[64 * 512];  // 64 KB
    const int t = threadIdx.x;
    const int mtile = blockIdx.x;
    {
        int row = t >> 2, seg = t & 3;
        const ushort_t* src = hid_bf + (size_t)(mtile * 64 + row) * 512 + seg * 128;
#pragma unroll
        for (int i = 0; i < 16; i++) {
            uint4 v = *(const uint4*)(src + i * 8);
            int c = seg * 16 + i;
            *(uint4*)&As[row * 512 + ((c ^ (row & 7)) * 8)] = v;
        }
    }
    __syncthreads();
    const int wv = t >> 6, l = t & 63, kc = l >> 4, lr = l & 15;
    f32x4 zero = {0.f, 0.f, 0.f, 0.f};
    f32x4 acc[4][4];
#pragma unroll
    for (int i = 0; i < 4; i++)
#pragma unroll
        for (int jj = 0; jj < 4; jj++) acc[i][jj] = zero;
#pragma unroll
    for (int s = 0; s < 16; s++) {
        short8 bfr[4];
        const ushort_t* fp = w2fr + ((size_t)(wv * 16 + s) * 4) * 512 + l * 8;
#pragma unroll
        for (int ni = 0; ni < 4; ni++) bfr[ni] = *(const short8*)(fp + ni * 512);
        short8 af[4];
#pragma unroll
        for (int mi = 0; mi < 4; mi++) {
            int r2 = lr + mi * 16;
            int c = s * 4 + kc;
            af[mi] = *(const short8*)&As[r2 * 512 + ((c ^ (r2 & 7)) * 8)];
        }
#pragma unroll
        for (int mi = 0; mi < 4; mi++)
#pragma unroll
            for (int ni = 0; ni < 4; ni++)
                acc[mi][ni] = mfma_bf16(af[mi], bfr[ni], acc[mi][ni]);
    }
#pragma unroll
    for (int mi = 0; mi < 4; mi++)
#pragma unroll
        for (int ni = 0; ni < 4; ni++)
#pragma unroll
            for (int r = 0; r < 4; r++) {
                int rowg = mtile * 64 + mi * 16 + kc * 4 + r;
                int col = wv * 64 + ni * 16 + lr;
                outS[(size_t)rowg * 256 + col] =
                    acc[mi][ni][r] + b2[col] + SB[(size_t)rowg * 256 + col];
            }
}

// -------- host --------
extern "C" void kernel_launch(void* const* d_in, const int* in_sizes, int n_in,
                              void* d_out, int out_size, void* d_ws, size_t ws_size,
                              hipStream_t stream) {
    const float* inputs   = (const float*)d_in[0];
    const float* slots0   = (const float*)d_in[1];
    const float* ln_in_g  = (const float*)d_in[2];
    const float* ln_in_b  = (const float*)d_in[3];
    const float* ln_sl_g  = (const float*)d_in[4];
    const float* ln_sl_b  = (const float*)d_in[5];
    const float* ln_mlp_g = (const float*)d_in[6];
    const float* ln_mlp_b = (const float*)d_in[7];
    const float* Wq       = (const float*)d_in[8];
    const float* Wk       = (const float*)d_in[9];
    const float* Wv       = (const float*)d_in[10];
    const float* w_ih     = (const float*)d_in[11];
    const float* w_hh     = (const float*)d_in[12];
    const float* b_ih     = (const float*)d_in[13];
    const float* b_hh     = (const float*)d_in[14];
    const float* w1       = (const float*)d_in[15];
    const float* b1       = (const float*)d_in[16];
    const float* w2       = (const float*)d_in[17];
    const float* b2       = (const float*)d_in[18];

    float* out_slots = (float*)d_out;
    float* out_vis   = (float*)d_out + 64 * 8 * 256;

    char* p = (char*)d_ws;
    auto carve = [&](size_t bytes) {
        void* r = (void*)p;
        p += (bytes + 255) & ~(size_t)255;
        return r;
    };
    ushort_t* kv    = (ushort_t*)carve((size_t)65536 * 512 * 2);   // 64 MB
    ushort_t* Wt    = (ushort_t*)carve((size_t)512 * 256 * 2);
    ushort_t* Wtp   = (ushort_t*)carve((size_t)512 * 256 * 2);
    ushort_t* ihfr  = (ushort_t*)carve((size_t)768 * 256 * 2);
    ushort_t* hhfr  = (ushort_t*)carve((size_t)768 * 256 * 2);
    ushort_t* w1fr  = (ushort_t*)carve((size_t)512 * 256 * 2);
    ushort_t* w2fr  = (ushort_t*)carve((size_t)256 * 512 * 2);
    float* qp       = (float*)carve((size_t)64 * 2048 * 4);
    float* Upart    = (float*)carve((size_t)64 * 8 * 2048 * 4);    // 4 MB
    float* Cpart    = (float*)carve((size_t)64 * 8 * 32 * 4);
    float* gg       = (float*)carve((size_t)512 * 1536 * 4);       // 3 MB
    float* SB       = (float*)carve((size_t)512 * 256 * 4);
    float* slotsA   = (float*)carve((size_t)512 * 256 * 4);
    ushort_t* U_bf  = (ushort_t*)carve((size_t)512 * 256 * 2);
    ushort_t* H_bf  = (ushort_t*)carve((size_t)512 * 256 * 2);
    ushort_t* M_bf  = (ushort_t*)carve((size_t)512 * 256 * 2);
    ushort_t* hid_bf = (ushort_t*)carve((size_t)512 * 512 * 2);

    prepack_w_kernel<<<512, 256, 0, stream>>>(Wk, Wv, Wt);
    prepack_wtp_kernel<<<64, 256, 0, stream>>>(Wt, Wtp);
    prepack_frags_kernel<<<dim3(96, 4), 256, 0, stream>>>(w_ih, w_hh, w1, w2,
                                                          ihfr, hhfr, w1fr, w2fr);
    kvproj_mfma_kernel<<<1024, 512, 0, stream>>>(inputs, ln_in_g, ln_in_b, Wtp, kv);
    qproj_kernel<<<512, 256, 0, stream>>>(slots0, ln_sl_g, ln_sl_b, Wq, qp);

    for (int it = 0; it < 3; ++it) {
        const float* slotsIn = (it == 0) ? slots0 : slotsA;
        float* slotsOut = (it == 2) ? out_slots : slotsA;
        attn_fused_kernel<<<dim3(8, 64), 256, 0, stream>>>(kv, qp, Upart, Cpart, out_vis,
                                                           (it == 2) ? 1 : 0);
        updates_final_kernel<<<64, 256, 0, stream>>>(Upart, Cpart, slotsIn, U_bf, H_bf);
        gru_gemm_kernel<<<dim3(8, 3, 2), 256, 0, stream>>>(U_bf, H_bf, ihfr, hhfr,
                                                           b_ih, b_hh, gg);
        gate_ln_kernel<<<512, 256, 0, stream>>>(gg, slotsIn, ln_mlp_g, ln_mlp_b, SB, M_bf);
        mlp1_gemm_kernel<<<dim3(8, 2), 256, 0, stream>>>(M_bf, w1fr, b1, hid_bf);
        mlp2_gemm_kernel<<<8, 256, 0, stream>>>(hid_bf, w2fr, b2, SB, slotsOut);
        if (it < 2)
            qproj_kernel<<<512, 256, 0, stream>>>(slotsA, ln_sl_g, ln_sl_b, Wq, qp);
    }
}

// Round 10
// 212.482 us; speedup vs baseline: 1.4169x; 1.4169x over previous
//
#include <hip/hip_runtime.h>
#include <hip/hip_bf16.h>
#include <math.h>

#define EPS_  1e-8f
#define LNEPS 1e-5f

typedef __attribute__((ext_vector_type(8))) short   short8;
typedef __attribute__((ext_vector_type(8))) __bf16  bf16x8;
typedef __attribute__((ext_vector_type(4))) float   f32x4;
typedef unsigned short ushort_t;

__device__ __forceinline__ float bf2f(unsigned int u) { return __uint_as_float(u << 16); }
__device__ __forceinline__ unsigned short f2bf(float f) {
    unsigned int u = __float_as_uint(f);
    u += 0x7fff + ((u >> 16) & 1);
    return (unsigned short)(u >> 16);
}
__device__ __forceinline__ f32x4 mfma_bf16(short8 a, short8 b, f32x4 c) {
    union U { short8 s; bf16x8 b; };
    U ua, ub; ua.s = a; ub.s = b;
    return __builtin_amdgcn_mfma_f32_16x16x32_bf16(ua.b, ub.b, c, 0, 0, 0);
}
__device__ __forceinline__ float wred_sum(float v) {
#pragma unroll
    for (int off = 32; off > 0; off >>= 1) v += __shfl_xor(v, off);
    return v;
}

// -------- prepack Wk/Wv -> Wt[n][k] bf16 (k pre-scaled 0.125) --------
__global__ __launch_bounds__(256) void prepack_w_kernel(const float* __restrict__ Wk,
                                                        const float* __restrict__ Wv,
                                                        ushort_t* __restrict__ Wt) {
    int n = blockIdx.x;
    int k = threadIdx.x;
    float v = (n < 256) ? Wk[(size_t)k * 256 + n] * 0.125f : Wv[(size_t)k * 256 + (n - 256)];
    Wt[(size_t)n * 256 + k] = f2bf(v);
}

// -------- prepack Wt -> Wtp: per (wave,step,ni) 1KB block, lane-contiguous MFMA B-frags ----
__global__ __launch_bounds__(256) void prepack_wtp_kernel(const ushort_t* __restrict__ Wt,
                                                          ushort_t* __restrict__ Wtp) {
    int bs = blockIdx.x;              // wv*8+s, 0..63
    int wv = bs >> 3, s = bs & 7;
    int ni = threadIdx.x >> 6, l = threadIdx.x & 63;
    int n  = wv * 64 + ni * 16 + (l & 15);
    int k0 = s * 32 + (l >> 4) * 8;
    short8 v = *(const short8*)(Wt + (size_t)n * 256 + k0);
    *(short8*)(Wtp + ((size_t)bs * 4 + ni) * 512 + l * 8) = v;
}

// -------- prepack slot-chain weights to bf16 interleaved layouts --------
__global__ __launch_bounds__(512) void prepack_slotw_kernel(const float* __restrict__ w_ih,
                                                            const float* __restrict__ w_hh,
                                                            const float* __restrict__ w1,
                                                            const float* __restrict__ w2,
                                                            const float* __restrict__ Wq,
                                                            ushort_t* __restrict__ wg,
                                                            ushort_t* __restrict__ w1p,
                                                            ushort_t* __restrict__ w2q,
                                                            ushort_t* __restrict__ Wqp) {
    int t = threadIdx.x, bid = blockIdx.x, sec = blockIdx.y;
    if (sec == 0) {
        if (bid < 256) {
            int k = bid, c = t & 255;
            const float* src = (t >> 8) ? w_hh : w_ih;
            size_t o = ((size_t)k * 512 + t) * 4;
            wg[o + 0] = f2bf(src[(size_t)(0 * 256 + c) * 256 + k]);
            wg[o + 1] = f2bf(src[(size_t)(1 * 256 + c) * 256 + k]);
            wg[o + 2] = f2bf(src[(size_t)(2 * 256 + c) * 256 + k]);
            wg[o + 3] = 0;
        }
    } else if (sec == 1) {
        if (bid < 64) {
            size_t o = ((size_t)bid * 512 + t) * 4;
#pragma unroll
            for (int i = 0; i < 4; i++) w1p[o + i] = f2bf(w1[(size_t)(bid * 4 + i) * 512 + t]);
        }
    } else if (sec == 2) {
        if (bid < 64) {
            int k4g = bid * 2 + (t >> 8), c = t & 255;
            size_t o = ((size_t)k4g * 256 + c) * 4;
#pragma unroll
            for (int i = 0; i < 4; i++) w2q[o + i] = f2bf(w2[(size_t)(k4g * 4 + i) * 256 + c]);
        }
    } else {
        if (bid < 32) {
            int k4g = bid * 2 + (t >> 8), c = t & 255;
            size_t o = ((size_t)k4g * 256 + c) * 4;
#pragma unroll
            for (int i = 0; i < 4; i++) Wqp[o + i] = f2bf(Wq[(size_t)(k4g * 4 + i) * 256 + c]);
        }
    }
}

// -------- KV projection v6: v4 + wide swizzle + paired-lane packed stores --------
// 1024 blocks x 512 threads (8 waves). M-tile 64 rows; wave w owns n-cols [w*64, w*64+64).
__global__ __launch_bounds__(512, 4) void kvproj_mfma_kernel(const float* __restrict__ in,
                                                             const float* __restrict__ g,
                                                             const float* __restrict__ bb,
                                                             const ushort_t* __restrict__ Wtp,
                                                             ushort_t* __restrict__ kvout) {
    __shared__ __align__(16) ushort_t As[64 * 256];
    const int tid = threadIdx.x;
    const int wv = tid >> 6, l = tid & 63;
    const int kc = l >> 4, lr = l & 15;
    const int m0 = blockIdx.x * 64;

    // ---- A-stage: instruction i loads ONE row (i*8+wv) contiguously ----
    float4 g4 = *(const float4*)(g + l * 4);
    float4 b4 = *(const float4*)(bb + l * 4);
    float4 xv[8];
#pragma unroll
    for (int i = 0; i < 8; i++)
        xv[i] = *(const float4*)(in + (size_t)(m0 + i * 8 + wv) * 256 + l * 4);
#pragma unroll
    for (int i = 0; i < 8; i++) {
        float s1 = xv[i].x + xv[i].y + xv[i].z + xv[i].w;
        float s2 = xv[i].x * xv[i].x + xv[i].y * xv[i].y + xv[i].z * xv[i].z + xv[i].w * xv[i].w;
        s1 = wred_sum(s1);
        s2 = wred_sum(s2);
        float m = s1 * (1.0f / 256.0f);
        float r = rsqrtf(s2 * (1.0f / 256.0f) - m * m + LNEPS);
        unsigned int p0 = f2bf((xv[i].x - m) * r * g4.x + b4.x);
        unsigned int p1 = f2bf((xv[i].y - m) * r * g4.y + b4.y);
        unsigned int p2 = f2bf((xv[i].z - m) * r * g4.z + b4.z);
        unsigned int p3 = f2bf((xv[i].w - m) * r * g4.w + b4.w);
        uint2 pk = {p0 | (p1 << 16), p2 | (p3 << 16)};
        int row = i * 8 + wv;
        // chunk (l>>1) swizzled with full row&15 (wider than r5's row&7)
        *(uint2*)&As[row * 256 + (((l >> 1) ^ (row & 15)) * 8) + (l & 1) * 4] = pk;
    }
    __syncthreads();

    // ---- K-loop: B streamed from L2 via coalesced 1KB fragment loads ----
    f32x4 zero = {0.f, 0.f, 0.f, 0.f};
    f32x4 acc[4][4];
#pragma unroll
    for (int i = 0; i < 4; i++)
#pragma unroll
        for (int jj = 0; jj < 4; jj++) acc[i][jj] = zero;

#pragma unroll
    for (int s = 0; s < 8; s++) {
        short8 bfr[4];
        const ushort_t* wpb = Wtp + ((size_t)(wv * 8 + s) * 4) * 512 + l * 8;
#pragma unroll
        for (int ni = 0; ni < 4; ni++) bfr[ni] = *(const short8*)(wpb + ni * 512);
        short8 af[4];
#pragma unroll
        for (int mi = 0; mi < 4; mi++) {
            int r2 = lr + mi * 16;
            int c = s * 4 + kc;
            af[mi] = *(const short8*)&As[r2 * 256 + ((c ^ (r2 & 15)) * 8)];
        }
#pragma unroll
        for (int mi = 0; mi < 4; mi++)
#pragma unroll
            for (int ni = 0; ni < 4; ni++)
                acc[mi][ni] = mfma_bf16(af[mi], bfr[ni], acc[mi][ni]);
    }
    // ---- epilogue: pair lanes -> uint (2 cols) stores, rows split across the pair ----
    const int odd = l & 1;
    const int colbase = wv * 64;
#pragma unroll
    for (int mi = 0; mi < 4; mi++)
#pragma unroll
        for (int ni = 0; ni < 4; ni++) {
            float s0 = odd ? acc[mi][ni][0] : acc[mi][ni][2];
            float s1_ = odd ? acc[mi][ni][1] : acc[mi][ni][3];
            float r0 = __shfl_xor(s0, 1);
            float r1_ = __shfl_xor(s1_, 1);
            int col0 = colbase + ni * 16 + (lr & ~1);
            unsigned int packA, packB;
            int rowA;
            if (!odd) {
                packA = (unsigned)f2bf(acc[mi][ni][0]) | ((unsigned)f2bf(r0) << 16);
                packB = (unsigned)f2bf(acc[mi][ni][1]) | ((unsigned)f2bf(r1_) << 16);
                rowA = m0 + mi * 16 + kc * 4 + 0;
            } else {
                packA = (unsigned)f2bf(r0) | ((unsigned)f2bf(acc[mi][ni][2]) << 16);
                packB = (unsigned)f2bf(r1_) | ((unsigned)f2bf(acc[mi][ni][3]) << 16);
                rowA = m0 + mi * 16 + kc * 4 + 2;
            }
            *(unsigned int*)(kvout + (size_t)rowA * 512 + col0) = packA;
            *(unsigned int*)(kvout + (size_t)(rowA + 1) * 512 + col0) = packB;
        }
}

// -------- initial slot LN + q projection (once). grid 512 x 256 --------
__global__ __launch_bounds__(256) void qproj_kernel(const float* __restrict__ slots,
                                                    const float* __restrict__ g,
                                                    const float* __restrict__ bvec,
                                                    const float* __restrict__ Wq,
                                                    float* __restrict__ qp) {
    int row = blockIdx.x;
    int tid = threadIdx.x;
    __shared__ float s_s[256];
    __shared__ float red[8];
    float x = slots[(size_t)row * 256 + tid];
    float s1 = wred_sum(x);
    float s2 = wred_sum(x * x);
    if ((tid & 63) == 0) { red[tid >> 6] = s1; red[4 + (tid >> 6)] = s2; }
    __syncthreads();
    float m  = (red[0] + red[1] + red[2] + red[3]) * (1.0f / 256.0f);
    float e2 = (red[4] + red[5] + red[6] + red[7]) * (1.0f / 256.0f);
    float rst = rsqrtf(e2 - m * m + LNEPS);
    s_s[tid] = (x - m) * rst * g[tid] + bvec[tid];
    __syncthreads();
    float acc = 0.f;
#pragma unroll 4
    for (int d = 0; d < 256; d++) acc += s_s[d] * Wq[(size_t)d * 256 + tid];
    int b = row >> 3, q = row & 7;
    qp[((size_t)(b * 4 + (tid >> 6)) * 8 + q) * 64 + (tid & 63)] = acc;
}

// -------- fused attention v4: MFMA logits + softmax + V accum + in-block U reduce --------
// grid (8 chunks of 128 tokens, 64 b) x 256 threads (4 waves).
__global__ __launch_bounds__(256) void attn_fused_kernel(const ushort_t* __restrict__ kv,
                                                         const float* __restrict__ qp,
                                                         float* __restrict__ Upart,
                                                         float* __restrict__ Cpart,
                                                         float* __restrict__ vis,
                                                         int write_vis) {
    int b = blockIdx.y;
    int chunk = blockIdx.x;
    int tid = threadIdx.x;
    __shared__ __align__(16) ushort_t qfrag[16 * 512];  // 16 KB
    __shared__ float att[128][32];                      // 16 KB
    __shared__ float ubuf[2][2048];                     // 16 KB
    __shared__ float cred[8][32];

    {
        const float* qb_ = qp + (size_t)b * 2048;
#pragma unroll
        for (int snt = 0; snt < 16; snt++) {
            int s = snt >> 1, nt = snt & 1;
#pragma unroll
            for (int rep = 0; rep < 2; rep++) {
                int idx = tid + rep * 256;  // 0..511
                int k  = s * 32 + ((idx >> 7) << 3) + (idx & 7);
                int hq = nt * 16 + ((idx >> 3) & 15);
                float v = ((k >> 6) == (hq >> 3))
                              ? qb_[(hq >> 3) * 512 + (hq & 7) * 64 + (k & 63)] : 0.f;
                qfrag[snt * 512 + idx] = f2bf(v);
            }
        }
    }
    __syncthreads();

    const int w = tid >> 6, l = tid & 63;
    const int lr = l & 15, kc8 = (l >> 4) * 8;

    short8 qb2[2][8];
#pragma unroll
    for (int s = 0; s < 8; s++) {
        qb2[0][s] = *(const short8*)&qfrag[(s * 2 + 0) * 512 + l * 8];
        qb2[1][s] = *(const short8*)&qfrag[(s * 2 + 1) * 512 + l * 8];
    }
    f32x4 zero = {0.f, 0.f, 0.f, 0.f};
#pragma unroll
    for (int mi_loc = 0; mi_loc < 2; mi_loc++) {
        int mi = w * 2 + mi_loc;
        f32x4 a0 = zero, a1 = zero;
        const ushort_t* abase = kv + (size_t)(b * 1024 + chunk * 128 + mi * 16 + lr) * 512 + kc8;
#pragma unroll
        for (int s = 0; s < 8; s++) {
            short8 af = *(const short8*)(abase + s * 32);
            a0 = mfma_bf16(af, qb2[0][s], a0);
            a1 = mfma_bf16(af, qb2[1][s], a1);
        }
        int row0 = mi * 16 + (l >> 4) * 4;
#pragma unroll
        for (int r = 0; r < 4; r++) {
            att[row0 + r][lr]      = a0[r];
            att[row0 + r][16 + lr] = a1[r];
        }
    }
    __syncthreads();

    {
        int token = tid >> 1, half = tid & 1;
        float v[16];
        float mx = -3.4e38f;
#pragma unroll
        for (int j = 0; j < 16; j++) { v[j] = att[token][half * 16 + j]; mx = fmaxf(mx, v[j]); }
        mx = fmaxf(mx, __shfl_xor(mx, 1));
        float sm = 0.f;
#pragma unroll
        for (int j = 0; j < 16; j++) { v[j] = __expf(v[j] - mx); sm += v[j]; }
        sm += __shfl_xor(sm, 1);
        float inv = 1.0f / sm;
#pragma unroll
        for (int j = 0; j < 16; j++) { v[j] *= inv; att[token][half * 16 + j] = v[j] + EPS_; }
        if (write_vis) {
#pragma unroll
            for (int q = 0; q < 8; q++) {
                float pv = v[q] + v[q + 8];
                float pf = pv + __shfl_xor(pv, 1);
                if (half == 0) vis[(size_t)(b * 8 + q) * 1024 + chunk * 128 + token] = pf;
            }
        }
    }
    __syncthreads();

    {
        int hq2 = tid & 31, grp = tid >> 5;
        float s = 0.f;
#pragma unroll
        for (int i = 0; i < 16; i++) s += att[grp * 16 + i][hq2];
        cred[grp][hq2] = s;
    }
    __syncthreads();
    if (tid < 32) {
        float s = 0.f;
#pragma unroll
        for (int g2 = 0; g2 < 8; g2++) s += cred[g2][tid];
        Cpart[(size_t)(b * 8 + chunk) * 32 + tid] = s;
    }

    const int h_u = l >> 4, d4 = l & 15;
    const int uo = h_u * 64 + d4 * 4;
    float U[8][4];
#pragma unroll
    for (int q = 0; q < 8; q++)
#pragma unroll
        for (int d = 0; d < 4; d++) U[q][d] = 0.f;
    const ushort_t* vbase = kv + (size_t)(b * 1024 + chunk * 128 + w * 32) * 512 + 256 + uo;
    for (int i = 0; i < 32; ++i) {
        uint2 vp = *(const uint2*)(vbase + (size_t)i * 512);
        float v0 = bf2f(vp.x & 0xffffu), v1 = bf2f(vp.x >> 16);
        float v2 = bf2f(vp.y & 0xffffu), v3 = bf2f(vp.y >> 16);
        const float* arow = &att[w * 32 + i][h_u * 8];
        float4 a01 = *(const float4*)(arow);
        float4 a23 = *(const float4*)(arow + 4);
        float aq[8] = {a01.x, a01.y, a01.z, a01.w, a23.x, a23.y, a23.z, a23.w};
#pragma unroll
        for (int q = 0; q < 8; q++) {
            U[q][0] += aq[q] * v0; U[q][1] += aq[q] * v1;
            U[q][2] += aq[q] * v2; U[q][3] += aq[q] * v3;
        }
    }
    if (w & 1) {
        float* dst = ubuf[w >> 1];
#pragma unroll
        for (int q = 0; q < 8; q++) {
            float4 uq = {U[q][0], U[q][1], U[q][2], U[q][3]};
            *(float4*)(dst + q * 256 + uo) = uq;
        }
    }
    __syncthreads();
    if (!(w & 1)) {
        const float* src = ubuf[w >> 1];
#pragma unroll
        for (int q = 0; q < 8; q++) {
            float4 uq = *(const float4*)(src + q * 256 + uo);
            U[q][0] += uq.x; U[q][1] += uq.y; U[q][2] += uq.z; U[q][3] += uq.w;
        }
    }
    __syncthreads();
    if (w == 2) {
        float* dst = ubuf[0];
#pragma unroll
        for (int q = 0; q < 8; q++) {
            float4 uq = {U[q][0], U[q][1], U[q][2], U[q][3]};
            *(float4*)(dst + q * 256 + uo) = uq;
        }
    }
    __syncthreads();
    if (w == 0) {
        const float* src = ubuf[0];
        float* up = Upart + (size_t)(b * 8 + chunk) * 2048 + uo;
#pragma unroll
        for (int q = 0; q < 8; q++) {
            float4 uq = *(const float4*)(src + q * 256 + uo);
            float4 o = {U[q][0] + uq.x, U[q][1] + uq.y, U[q][2] + uq.z, U[q][3] + uq.w};
            *(float4*)(up + q * 256) = o;
        }
    }
}

// -------- fused slot update v4: 1024 threads, k-split GEMVs, reg-batched weight loads --------
// 256 blocks x 1024 threads; 2 rows per block.
__global__ __launch_bounds__(1024) void slot_fused_kernel(const float* __restrict__ Upart,
                                                          const float* __restrict__ Cpart,
                                                          const float* __restrict__ slotsIn,
                                                          const ushort_t* __restrict__ wg,
                                                          const float* __restrict__ b_ih,
                                                          const float* __restrict__ b_hh,
                                                          const float* __restrict__ ln_mlp_g,
                                                          const float* __restrict__ ln_mlp_b,
                                                          const ushort_t* __restrict__ w1p,
                                                          const float* __restrict__ b1,
                                                          const ushort_t* __restrict__ w2q,
                                                          const float* __restrict__ b2,
                                                          const float* __restrict__ ln_sl_g,
                                                          const float* __restrict__ ln_sl_b,
                                                          const ushort_t* __restrict__ Wqp,
                                                          float* __restrict__ slotsOut,
                                                          float* __restrict__ qp,
                                                          int emit_qp) {
    __shared__ float U_s[2][256], H_s[2][256];
    __shared__ float rsum[2][2][256];
    __shared__ float gpart[2][12][256];   // [kh][mh*6+gate*2+row][c]
    __shared__ float SB_s[2][256], M_s[2][256];
    __shared__ float hid_s[2][512];
    __shared__ float mpart[2][2][512];
    __shared__ float ppart[4][2][256];
    __shared__ float redA[8], redB[8];
    const int t = threadIdx.x;
    const int kh = t >> 9, s9 = t & 511;
    const int rr = s9 >> 8, c = s9 & 255;
    const int lane = t & 63, wvi = t >> 6;
    const int r0 = blockIdx.x * 2;
    const int rg = r0 + rr, bb_ = rg >> 3, q = rg & 7;

    // ---- phase 0: Upart reduce (k-split over partial sets) + normalize ----
    {
        float s = 0.f;
#pragma unroll
        for (int p2 = 0; p2 < 4; p2++)
            s += Upart[(size_t)(bb_ * 8 + kh * 4 + p2) * 2048 + q * 256 + c];
        rsum[kh][rr][c] = s;
    }
    __syncthreads();
    if (kh == 0) {
        int h = c >> 6;
        float C = 0.f;
#pragma unroll
        for (int p2 = 0; p2 < 8; p2++)
            C += Cpart[(size_t)(bb_ * 8 + p2) * 32 + h * 8 + q];
        U_s[rr][c] = (rsum[0][rr][c] + rsum[1][rr][c]) / C;
        H_s[rr][c] = slotsIn[(size_t)rg * 256 + c];
    }
    __syncthreads();

    // ---- GRU GEMV: thread (kh, mh=rr, c); k in [kh*128, kh*128+128) ----
    {
        float ar0, az0, an0;
        if (kh == 0) {
            const float* bias = rr ? b_hh : b_ih;
            ar0 = bias[c]; az0 = bias[256 + c]; an0 = bias[512 + c];
        } else { ar0 = az0 = an0 = 0.f; }
        float ar1 = ar0, az1 = az0, an1 = an0;
        const float (*act)[256] = rr ? H_s : U_s;
        const ushort_t* wp = wg + (size_t)s9 * 4;
        for (int cc = 0; cc < 8; cc++) {
            uint2 wreg[16];
#pragma unroll
            for (int i = 0; i < 16; i++) {
                int k = kh * 128 + cc * 16 + i;
                wreg[i] = *(const uint2*)(wp + (size_t)k * 2048);
            }
#pragma unroll
            for (int i = 0; i < 16; i++) {
                int k = kh * 128 + cc * 16 + i;
                float w0  = bf2f(wreg[i].x & 0xffffu);
                float w1_ = bf2f(wreg[i].x >> 16);
                float w2_ = bf2f(wreg[i].y & 0xffffu);
                float a0 = act[0][k], a1 = act[1][k];
                ar0 += a0 * w0; az0 += a0 * w1_; an0 += a0 * w2_;
                ar1 += a1 * w0; az1 += a1 * w1_; an1 += a1 * w2_;
            }
        }
        gpart[kh][rr * 6 + 0][c] = ar0; gpart[kh][rr * 6 + 1][c] = ar1;
        gpart[kh][rr * 6 + 2][c] = az0; gpart[kh][rr * 6 + 3][c] = az1;
        gpart[kh][rr * 6 + 4][c] = an0; gpart[kh][rr * 6 + 5][c] = an1;
    }
    __syncthreads();

    // ---- gates + LN(mlp): kh==0 threads (8 full waves) ----
    float sb = 0.f;
    if (kh == 0) {
        float xr = gpart[0][0 + rr][c] + gpart[1][0 + rr][c];
        float xz = gpart[0][2 + rr][c] + gpart[1][2 + rr][c];
        float xn = gpart[0][4 + rr][c] + gpart[1][4 + rr][c];
        float hr = gpart[0][6 + rr][c] + gpart[1][6 + rr][c];
        float hz = gpart[0][8 + rr][c] + gpart[1][8 + rr][c];
        float hn = gpart[0][10 + rr][c] + gpart[1][10 + rr][c];
        float rg_ = 1.f / (1.f + __expf(-(xr + hr)));
        float z   = 1.f / (1.f + __expf(-(xz + hz)));
        float nn  = tanhf(xn + rg_ * hn);
        sb = (1.f - z) * nn + z * H_s[rr][c];
        SB_s[rr][c] = sb;
        float s1 = wred_sum(sb), s2 = wred_sum(sb * sb);
        if (lane == 0) { redA[wvi] = s1; redB[wvi] = s2; }
    }
    __syncthreads();
    if (kh == 0) {
        int base = rr * 4;
        float m  = (redA[base] + redA[base + 1] + redA[base + 2] + redA[base + 3]) * (1.f / 256.f);
        float e2 = (redB[base] + redB[base + 1] + redB[base + 2] + redB[base + 3]) * (1.f / 256.f);
        float rst = rsqrtf(e2 - m * m + LNEPS);
        M_s[rr][c] = (sb - m) * rst * ln_mlp_g[c] + ln_mlp_b[c];
    }
    __syncthreads();

    // ---- MLP1: thread (kh, col j=s9); k4 in [kh*32, kh*32+32) ----
    {
        float h10 = 0.f, h11 = 0.f;
        const ushort_t* wp = w1p + (size_t)s9 * 4;
        for (int cc = 0; cc < 2; cc++) {
            uint2 wreg[16];
#pragma unroll
            for (int i = 0; i < 16; i++) {
                int k4 = kh * 32 + cc * 16 + i;
                wreg[i] = *(const uint2*)(wp + (size_t)k4 * 2048);
            }
#pragma unroll
            for (int i = 0; i < 16; i++) {
                int k4 = kh * 32 + cc * 16 + i;
                float wA[4] = {bf2f(wreg[i].x & 0xffffu), bf2f(wreg[i].x >> 16),
                               bf2f(wreg[i].y & 0xffffu), bf2f(wreg[i].y >> 16)};
#pragma unroll
                for (int ii = 0; ii < 4; ii++) {
                    int k = k4 * 4 + ii;
                    h10 += M_s[0][k] * wA[ii];
                    h11 += M_s[1][k] * wA[ii];
                }
            }
        }
        mpart[kh][0][s9] = h10;
        mpart[kh][1][s9] = h11;
    }
    __syncthreads();
    if (kh == 0) {
        float bb1 = b1[s9];
        hid_s[0][s9] = fmaxf(mpart[0][0][s9] + mpart[1][0][s9] + bb1, 0.f);
        hid_s[1][s9] = fmaxf(mpart[0][1][s9] + mpart[1][1][s9] + bb1, 0.f);
    }
    __syncthreads();

    // ---- MLP2: thread (q2=kh*2+rr, c); k4g in [q2*32, q2*32+32) ----
    {
        int q2 = kh * 2 + rr;
        float p0 = 0.f, p1 = 0.f;
        const ushort_t* wp = w2q + (size_t)c * 4;
        for (int cc = 0; cc < 2; cc++) {
            uint2 wreg[16];
#pragma unroll
            for (int i = 0; i < 16; i++) {
                int k4g = q2 * 32 + cc * 16 + i;
                wreg[i] = *(const uint2*)(wp + (size_t)k4g * 1024);
            }
#pragma unroll
            for (int i = 0; i < 16; i++) {
                int k4g = q2 * 32 + cc * 16 + i;
                float wA[4] = {bf2f(wreg[i].x & 0xffffu), bf2f(wreg[i].x >> 16),
                               bf2f(wreg[i].y & 0xffffu), bf2f(wreg[i].y >> 16)};
#pragma unroll
                for (int ii = 0; ii < 4; ii++) {
                    int k = k4g * 4 + ii;
                    p0 += hid_s[0][k] * wA[ii];
                    p1 += hid_s[1][k] * wA[ii];
                }
            }
        }
        ppart[q2][0][c] = p0;
        ppart[q2][1][c] = p1;
    }
    __syncthreads();
    float outv = 0.f;
    if (kh == 0) {
        outv = ppart[0][rr][c] + ppart[1][rr][c] + ppart[2][rr][c] + ppart[3][rr][c]
             + b2[c] + SB_s[rr][c];
        slotsOut[(size_t)rg * 256 + c] = outv;
    }

    if (emit_qp) {
        __syncthreads();
        if (kh == 0) {
            float s1 = wred_sum(outv), s2 = wred_sum(outv * outv);
            if (lane == 0) { redA[wvi] = s1; redB[wvi] = s2; }
        }
        __syncthreads();
        if (kh == 0) {
            int base = rr * 4;
            float m  = (redA[base] + redA[base + 1] + redA[base + 2] + redA[base + 3]) * (1.f / 256.f);
            float e2 = (redB[base] + redB[base + 1] + redB[base + 2] + redB[base + 3]) * (1.f / 256.f);
            float rst = rsqrtf(e2 - m * m + LNEPS);
            M_s[rr][c] = (outv - m) * rst * ln_sl_g[c] + ln_sl_b[c];
        }
        __syncthreads();
        {
            int q2 = kh * 2 + rr;
            float p0 = 0.f, p1 = 0.f;
            const ushort_t* wp = Wqp + (size_t)c * 4;
            uint2 wreg[16];
#pragma unroll
            for (int i = 0; i < 16; i++) {
                int k4g = q2 * 16 + i;
                wreg[i] = *(const uint2*)(wp + (size_t)k4g * 1024);
            }
#pragma unroll
            for (int i = 0; i < 16; i++) {
                int k4g = q2 * 16 + i;
                float wA[4] = {bf2f(wreg[i].x & 0xffffu), bf2f(wreg[i].x >> 16),
                               bf2f(wreg[i].y & 0xffffu), bf2f(wreg[i].y >> 16)};
#pragma unroll
                for (int ii = 0; ii < 4; ii++) {
                    int k = k4g * 4 + ii;
                    p0 += M_s[0][k] * wA[ii];
                    p1 += M_s[1][k] * wA[ii];
                }
            }
            ppart[q2][0][c] = p0;
            ppart[q2][1][c] = p1;
        }
        __syncthreads();
        if (kh == 0) {
            float qv = ppart[0][rr][c] + ppart[1][rr][c] + ppart[2][rr][c] + ppart[3][rr][c];
            qp[(size_t)bb_ * 2048 + (c >> 6) * 512 + q * 64 + (c & 63)] = qv;
        }
    }
}

// -------- host --------
extern "C" void kernel_launch(void* const* d_in, const int* in_sizes, int n_in,
                              void* d_out, int out_size, void* d_ws, size_t ws_size,
                              hipStream_t stream) {
    const float* inputs   = (const float*)d_in[0];
    const float* slots0   = (const float*)d_in[1];
    const float* ln_in_g  = (const float*)d_in[2];
    const float* ln_in_b  = (const float*)d_in[3];
    const float* ln_sl_g  = (const float*)d_in[4];
    const float* ln_sl_b  = (const float*)d_in[5];
    const float* ln_mlp_g = (const float*)d_in[6];
    const float* ln_mlp_b = (const float*)d_in[7];
    const float* Wq       = (const float*)d_in[8];
    const float* Wk       = (const float*)d_in[9];
    const float* Wv       = (const float*)d_in[10];
    const float* w_ih     = (const float*)d_in[11];
    const float* w_hh     = (const float*)d_in[12];
    const float* b_ih     = (const float*)d_in[13];
    const float* b_hh     = (const float*)d_in[14];
    const float* w1       = (const float*)d_in[15];
    const float* b1       = (const float*)d_in[16];
    const float* w2       = (const float*)d_in[17];
    const float* b2       = (const float*)d_in[18];

    float* out_slots = (float*)d_out;
    float* out_vis   = (float*)d_out + 64 * 8 * 256;

    char* p = (char*)d_ws;
    auto carve = [&](size_t bytes) {
        void* r = (void*)p;
        p += (bytes + 255) & ~(size_t)255;
        return r;
    };
    ushort_t* kv   = (ushort_t*)carve((size_t)65536 * 512 * 2);   // 64 MB
    ushort_t* Wt   = (ushort_t*)carve((size_t)512 * 256 * 2);
    ushort_t* Wtp  = (ushort_t*)carve((size_t)512 * 256 * 2);
    ushort_t* wg   = (ushort_t*)carve((size_t)256 * 512 * 4 * 2);
    ushort_t* w1p  = (ushort_t*)carve((size_t)64 * 512 * 4 * 2);
    ushort_t* w2q  = (ushort_t*)carve((size_t)128 * 256 * 4 * 2);
    ushort_t* Wqp  = (ushort_t*)carve((size_t)64 * 256 * 4 * 2);
    float* qp      = (float*)carve((size_t)64 * 2048 * 4);
    float* Upart   = (float*)carve((size_t)64 * 8 * 2048 * 4);    // 4 MB
    float* Cpart   = (float*)carve((size_t)64 * 8 * 32 * 4);
    float* slotsA  = (float*)carve((size_t)512 * 256 * 4);

    prepack_w_kernel<<<512, 256, 0, stream>>>(Wk, Wv, Wt);
    prepack_wtp_kernel<<<64, 256, 0, stream>>>(Wt, Wtp);
    prepack_slotw_kernel<<<dim3(256, 4), 512, 0, stream>>>(w_ih, w_hh, w1, w2, Wq,
                                                           wg, w1p, w2q, Wqp);
    kvproj_mfma_kernel<<<1024, 512, 0, stream>>>(inputs, ln_in_g, ln_in_b, Wtp, kv);
    qproj_kernel<<<512, 256, 0, stream>>>(slots0, ln_sl_g, ln_sl_b, Wq, qp);

    for (int it = 0; it < 3; ++it) {
        attn_fused_kernel<<<dim3(8, 64), 256, 0, stream>>>(kv, qp, Upart, Cpart, out_vis,
                                                           (it == 2) ? 1 : 0);
        slot_fused_kernel<<<256, 1024, 0, stream>>>(
            Upart, Cpart, (it == 0) ? slots0 : slotsA,
            wg, b_ih, b_hh, ln_mlp_g, ln_mlp_b, w1p, b1, w2q, b2,
            ln_sl_g, ln_sl_b, Wqp,
            (it == 2) ? out_slots : slotsA, qp, (it < 2) ? 1 : 0);
    }
}

// Round 11
// 210.723 us; speedup vs baseline: 1.4288x; 1.0083x over previous
//
#include <hip/hip_runtime.h>
#include <hip/hip_bf16.h>
#include <math.h>

#define EPS_  1e-8f
#define LNEPS 1e-5f

typedef __attribute__((ext_vector_type(8))) short   short8;
typedef __attribute__((ext_vector_type(8))) __bf16  bf16x8;
typedef __attribute__((ext_vector_type(4))) float   f32x4;
typedef unsigned short ushort_t;

__device__ __forceinline__ float bf2f(unsigned int u) { return __uint_as_float(u << 16); }
__device__ __forceinline__ unsigned short f2bf(float f) {
    unsigned int u = __float_as_uint(f);
    u += 0x7fff + ((u >> 16) & 1);
    return (unsigned short)(u >> 16);
}
__device__ __forceinline__ unsigned int cvt_pk_bf16(float lo, float hi) {
    unsigned int r;
    asm("v_cvt_pk_bf16_f32 %0, %1, %2" : "=v"(r) : "v"(lo), "v"(hi));
    return r;
}
__device__ __forceinline__ f32x4 mfma_bf16(short8 a, short8 b, f32x4 c) {
    union U { short8 s; bf16x8 b; };
    U ua, ub; ua.s = a; ub.s = b;
    return __builtin_amdgcn_mfma_f32_16x16x32_bf16(ua.b, ub.b, c, 0, 0, 0);
}
__device__ __forceinline__ float wred_sum(float v) {
#pragma unroll
    for (int off = 32; off > 0; off >>= 1) v += __shfl_xor(v, off);
    return v;
}

// -------- prepack Wk/Wv -> Wt[n][k] bf16 (k pre-scaled 0.125) --------
__global__ __launch_bounds__(256) void prepack_w_kernel(const float* __restrict__ Wk,
                                                        const float* __restrict__ Wv,
                                                        ushort_t* __restrict__ Wt) {
    int n = blockIdx.x;
    int k = threadIdx.x;
    float v = (n < 256) ? Wk[(size_t)k * 256 + n] * 0.125f : Wv[(size_t)k * 256 + (n - 256)];
    Wt[(size_t)n * 256 + k] = f2bf(v);
}

// -------- prepack Wt -> Wtp: per (wave,step,ni) 1KB block, lane-contiguous MFMA B-frags ----
__global__ __launch_bounds__(256) void prepack_wtp_kernel(const ushort_t* __restrict__ Wt,
                                                          ushort_t* __restrict__ Wtp) {
    int bs = blockIdx.x;              // wv*8+s, 0..63
    int wv = bs >> 3, s = bs & 7;
    int ni = threadIdx.x >> 6, l = threadIdx.x & 63;
    int n  = wv * 64 + ni * 16 + (l & 15);
    int k0 = s * 32 + (l >> 4) * 8;
    short8 v = *(const short8*)(Wt + (size_t)n * 256 + k0);
    *(short8*)(Wtp + ((size_t)bs * 4 + ni) * 512 + l * 8) = v;
}

// -------- prepack slot-chain weights to bf16 interleaved layouts --------
__global__ __launch_bounds__(512) void prepack_slotw_kernel(const float* __restrict__ w_ih,
                                                            const float* __restrict__ w_hh,
                                                            const float* __restrict__ w1,
                                                            const float* __restrict__ w2,
                                                            const float* __restrict__ Wq,
                                                            ushort_t* __restrict__ wg,
                                                            ushort_t* __restrict__ w1p,
                                                            ushort_t* __restrict__ w2q,
                                                            ushort_t* __restrict__ Wqp) {
    int t = threadIdx.x, bid = blockIdx.x, sec = blockIdx.y;
    if (sec == 0) {
        if (bid < 256) {
            int k = bid, c = t & 255;
            const float* src = (t >> 8) ? w_hh : w_ih;
            size_t o = ((size_t)k * 512 + t) * 4;
            wg[o + 0] = f2bf(src[(size_t)(0 * 256 + c) * 256 + k]);
            wg[o + 1] = f2bf(src[(size_t)(1 * 256 + c) * 256 + k]);
            wg[o + 2] = f2bf(src[(size_t)(2 * 256 + c) * 256 + k]);
            wg[o + 3] = 0;
        }
    } else if (sec == 1) {
        if (bid < 64) {
            size_t o = ((size_t)bid * 512 + t) * 4;
#pragma unroll
            for (int i = 0; i < 4; i++) w1p[o + i] = f2bf(w1[(size_t)(bid * 4 + i) * 512 + t]);
        }
    } else if (sec == 2) {
        if (bid < 64) {
            int k4g = bid * 2 + (t >> 8), c = t & 255;
            size_t o = ((size_t)k4g * 256 + c) * 4;
#pragma unroll
            for (int i = 0; i < 4; i++) w2q[o + i] = f2bf(w2[(size_t)(k4g * 4 + i) * 256 + c]);
        }
    } else {
        if (bid < 32) {
            int k4g = bid * 2 + (t >> 8), c = t & 255;
            size_t o = ((size_t)k4g * 256 + c) * 4;
#pragma unroll
            for (int i = 0; i < 4; i++) Wqp[o + i] = f2bf(Wq[(size_t)(k4g * 4 + i) * 256 + c]);
        }
    }
}

// -------- KV projection v7: v6 + register-double-buffered B-stream + cvt_pk packs --------
// 1024 blocks x 512 threads (8 waves). M-tile 64 rows; wave w owns n-cols [w*64, w*64+64).
__global__ __launch_bounds__(512, 4) void kvproj_mfma_kernel(const float* __restrict__ in,
                                                             const float* __restrict__ g,
                                                             const float* __restrict__ bb,
                                                             const ushort_t* __restrict__ Wtp,
                                                             ushort_t* __restrict__ kvout) {
    __shared__ __align__(16) ushort_t As[64 * 256];
    const int tid = threadIdx.x;
    const int wv = tid >> 6, l = tid & 63;
    const int kc = l >> 4, lr = l & 15;
    const int m0 = blockIdx.x * 64;

    // ---- A-stage: instruction i loads ONE row (i*8+wv) contiguously ----
    float4 g4 = *(const float4*)(g + l * 4);
    float4 b4 = *(const float4*)(bb + l * 4);
    float4 xv[8];
#pragma unroll
    for (int i = 0; i < 8; i++)
        xv[i] = *(const float4*)(in + (size_t)(m0 + i * 8 + wv) * 256 + l * 4);
#pragma unroll
    for (int i = 0; i < 8; i++) {
        float s1 = xv[i].x + xv[i].y + xv[i].z + xv[i].w;
        float s2 = xv[i].x * xv[i].x + xv[i].y * xv[i].y + xv[i].z * xv[i].z + xv[i].w * xv[i].w;
        s1 = wred_sum(s1);
        s2 = wred_sum(s2);
        float m = s1 * (1.0f / 256.0f);
        float r = rsqrtf(s2 * (1.0f / 256.0f) - m * m + LNEPS);
        float v0 = (xv[i].x - m) * r * g4.x + b4.x;
        float v1 = (xv[i].y - m) * r * g4.y + b4.y;
        float v2 = (xv[i].z - m) * r * g4.z + b4.z;
        float v3 = (xv[i].w - m) * r * g4.w + b4.w;
        uint2 pk = {cvt_pk_bf16(v0, v1), cvt_pk_bf16(v2, v3)};
        int row = i * 8 + wv;
        *(uint2*)&As[row * 256 + (((l >> 1) ^ (row & 15)) * 8) + (l & 1) * 4] = pk;
    }
    __syncthreads();

    // ---- K-loop: register double-buffered B fragments ----
    f32x4 zero = {0.f, 0.f, 0.f, 0.f};
    f32x4 acc[4][4];
#pragma unroll
    for (int i = 0; i < 4; i++)
#pragma unroll
        for (int jj = 0; jj < 4; jj++) acc[i][jj] = zero;

    const ushort_t* wbase = Wtp + ((size_t)(wv * 8) * 4) * 512 + l * 8;
    short8 bcur[4], bnxt[4];
#pragma unroll
    for (int ni = 0; ni < 4; ni++) bcur[ni] = *(const short8*)(wbase + ni * 512);

#pragma unroll
    for (int s = 0; s < 8; s++) {
        if (s < 7) {
            const ushort_t* wpb = wbase + (size_t)(s + 1) * 4 * 512;
#pragma unroll
            for (int ni = 0; ni < 4; ni++) bnxt[ni] = *(const short8*)(wpb + ni * 512);
        }
        short8 af[4];
#pragma unroll
        for (int mi = 0; mi < 4; mi++) {
            int r2 = lr + mi * 16;
            int c = s * 4 + kc;
            af[mi] = *(const short8*)&As[r2 * 256 + ((c ^ (r2 & 15)) * 8)];
        }
#pragma unroll
        for (int mi = 0; mi < 4; mi++)
#pragma unroll
            for (int ni = 0; ni < 4; ni++)
                acc[mi][ni] = mfma_bf16(af[mi], bcur[ni], acc[mi][ni]);
        if (s < 7) {
#pragma unroll
            for (int ni = 0; ni < 4; ni++) bcur[ni] = bnxt[ni];
        }
    }

    // ---- epilogue: pair lanes -> uint (2 cols) stores via cvt_pk ----
    const int odd = l & 1;
    const int colbase = wv * 64;
#pragma unroll
    for (int mi = 0; mi < 4; mi++)
#pragma unroll
        for (int ni = 0; ni < 4; ni++) {
            float s0 = odd ? acc[mi][ni][0] : acc[mi][ni][2];
            float s1_ = odd ? acc[mi][ni][1] : acc[mi][ni][3];
            float r0 = __shfl_xor(s0, 1);
            float r1_ = __shfl_xor(s1_, 1);
            int col0 = colbase + ni * 16 + (lr & ~1);
            unsigned int packA, packB;
            int rowA;
            if (!odd) {
                packA = cvt_pk_bf16(acc[mi][ni][0], r0);
                packB = cvt_pk_bf16(acc[mi][ni][1], r1_);
                rowA = m0 + mi * 16 + kc * 4 + 0;
            } else {
                packA = cvt_pk_bf16(r0, acc[mi][ni][2]);
                packB = cvt_pk_bf16(r1_, acc[mi][ni][3]);
                rowA = m0 + mi * 16 + kc * 4 + 2;
            }
            *(unsigned int*)(kvout + (size_t)rowA * 512 + col0) = packA;
            *(unsigned int*)(kvout + (size_t)(rowA + 1) * 512 + col0) = packB;
        }
}

// -------- initial slot LN + q projection (once). grid 512 x 256 --------
__global__ __launch_bounds__(256) void qproj_kernel(const float* __restrict__ slots,
                                                    const float* __restrict__ g,
                                                    const float* __restrict__ bvec,
                                                    const float* __restrict__ Wq,
                                                    float* __restrict__ qp) {
    int row = blockIdx.x;
    int tid = threadIdx.x;
    __shared__ float s_s[256];
    __shared__ float red[8];
    float x = slots[(size_t)row * 256 + tid];
    float s1 = wred_sum(x);
    float s2 = wred_sum(x * x);
    if ((tid & 63) == 0) { red[tid >> 6] = s1; red[4 + (tid >> 6)] = s2; }
    __syncthreads();
    float m  = (red[0] + red[1] + red[2] + red[3]) * (1.0f / 256.0f);
    float e2 = (red[4] + red[5] + red[6] + red[7]) * (1.0f / 256.0f);
    float rst = rsqrtf(e2 - m * m + LNEPS);
    s_s[tid] = (x - m) * rst * g[tid] + bvec[tid];
    __syncthreads();
    float acc = 0.f;
#pragma unroll 4
    for (int d = 0; d < 256; d++) acc += s_s[d] * Wq[(size_t)d * 256 + tid];
    int b = row >> 3, q = row & 7;
    qp[((size_t)(b * 4 + (tid >> 6)) * 8 + q) * 64 + (tid & 63)] = acc;
}

// -------- fused attention v4: MFMA logits + softmax + V accum + in-block U reduce --------
// grid (8 chunks of 128 tokens, 64 b) x 256 threads (4 waves).
__global__ __launch_bounds__(256) void attn_fused_kernel(const ushort_t* __restrict__ kv,
                                                         const float* __restrict__ qp,
                                                         float* __restrict__ Upart,
                                                         float* __restrict__ Cpart,
                                                         float* __restrict__ vis,
                                                         int write_vis) {
    int b = blockIdx.y;
    int chunk = blockIdx.x;
    int tid = threadIdx.x;
    __shared__ __align__(16) ushort_t qfrag[16 * 512];  // 16 KB
    __shared__ float att[128][32];                      // 16 KB
    __shared__ float ubuf[2][2048];                     // 16 KB
    __shared__ float cred[8][32];

    {
        const float* qb_ = qp + (size_t)b * 2048;
#pragma unroll
        for (int snt = 0; snt < 16; snt++) {
            int s = snt >> 1, nt = snt & 1;
#pragma unroll
            for (int rep = 0; rep < 2; rep++) {
                int idx = tid + rep * 256;  // 0..511
                int k  = s * 32 + ((idx >> 7) << 3) + (idx & 7);
                int hq = nt * 16 + ((idx >> 3) & 15);
                float v = ((k >> 6) == (hq >> 3))
                              ? qb_[(hq >> 3) * 512 + (hq & 7) * 64 + (k & 63)] : 0.f;
                qfrag[snt * 512 + idx] = f2bf(v);
            }
        }
    }
    __syncthreads();

    const int w = tid >> 6, l = tid & 63;
    const int lr = l & 15, kc8 = (l >> 4) * 8;

    short8 qb2[2][8];
#pragma unroll
    for (int s = 0; s < 8; s++) {
        qb2[0][s] = *(const short8*)&qfrag[(s * 2 + 0) * 512 + l * 8];
        qb2[1][s] = *(const short8*)&qfrag[(s * 2 + 1) * 512 + l * 8];
    }
    f32x4 zero = {0.f, 0.f, 0.f, 0.f};
#pragma unroll
    for (int mi_loc = 0; mi_loc < 2; mi_loc++) {
        int mi = w * 2 + mi_loc;
        f32x4 a0 = zero, a1 = zero;
        const ushort_t* abase = kv + (size_t)(b * 1024 + chunk * 128 + mi * 16 + lr) * 512 + kc8;
#pragma unroll
        for (int s = 0; s < 8; s++) {
            short8 af = *(const short8*)(abase + s * 32);
            a0 = mfma_bf16(af, qb2[0][s], a0);
            a1 = mfma_bf16(af, qb2[1][s], a1);
        }
        int row0 = mi * 16 + (l >> 4) * 4;
#pragma unroll
        for (int r = 0; r < 4; r++) {
            att[row0 + r][lr]      = a0[r];
            att[row0 + r][16 + lr] = a1[r];
        }
    }
    __syncthreads();

    {
        int token = tid >> 1, half = tid & 1;
        float v[16];
        float mx = -3.4e38f;
#pragma unroll
        for (int j = 0; j < 16; j++) { v[j] = att[token][half * 16 + j]; mx = fmaxf(mx, v[j]); }
        mx = fmaxf(mx, __shfl_xor(mx, 1));
        float sm = 0.f;
#pragma unroll
        for (int j = 0; j < 16; j++) { v[j] = __expf(v[j] - mx); sm += v[j]; }
        sm += __shfl_xor(sm, 1);
        float inv = 1.0f / sm;
#pragma unroll
        for (int j = 0; j < 16; j++) { v[j] *= inv; att[token][half * 16 + j] = v[j] + EPS_; }
        if (write_vis) {
#pragma unroll
            for (int q = 0; q < 8; q++) {
                float pv = v[q] + v[q + 8];
                float pf = pv + __shfl_xor(pv, 1);
                if (half == 0) vis[(size_t)(b * 8 + q) * 1024 + chunk * 128 + token] = pf;
            }
        }
    }
    __syncthreads();

    {
        int hq2 = tid & 31, grp = tid >> 5;
        float s = 0.f;
#pragma unroll
        for (int i = 0; i < 16; i++) s += att[grp * 16 + i][hq2];
        cred[grp][hq2] = s;
    }
    __syncthreads();
    if (tid < 32) {
        float s = 0.f;
#pragma unroll
        for (int g2 = 0; g2 < 8; g2++) s += cred[g2][tid];
        Cpart[(size_t)(b * 8 + chunk) * 32 + tid] = s;
    }

    const int h_u = l >> 4, d4 = l & 15;
    const int uo = h_u * 64 + d4 * 4;
    float U[8][4];
#pragma unroll
    for (int q = 0; q < 8; q++)
#pragma unroll
        for (int d = 0; d < 4; d++) U[q][d] = 0.f;
    const ushort_t* vbase = kv + (size_t)(b * 1024 + chunk * 128 + w * 32) * 512 + 256 + uo;
    for (int i = 0; i < 32; ++i) {
        uint2 vp = *(const uint2*)(vbase + (size_t)i * 512);
        float v0 = bf2f(vp.x & 0xffffu), v1 = bf2f(vp.x >> 16);
        float v2 = bf2f(vp.y & 0xffffu), v3 = bf2f(vp.y >> 16);
        const float* arow = &att[w * 32 + i][h_u * 8];
        float4 a01 = *(const float4*)(arow);
        float4 a23 = *(const float4*)(arow + 4);
        float aq[8] = {a01.x, a01.y, a01.z, a01.w, a23.x, a23.y, a23.z, a23.w};
#pragma unroll
        for (int q = 0; q < 8; q++) {
            U[q][0] += aq[q] * v0; U[q][1] += aq[q] * v1;
            U[q][2] += aq[q] * v2; U[q][3] += aq[q] * v3;
        }
    }
    if (w & 1) {
        float* dst = ubuf[w >> 1];
#pragma unroll
        for (int q = 0; q < 8; q++) {
            float4 uq = {U[q][0], U[q][1], U[q][2], U[q][3]};
            *(float4*)(dst + q * 256 + uo) = uq;
        }
    }
    __syncthreads();
    if (!(w & 1)) {
        const float* src = ubuf[w >> 1];
#pragma unroll
        for (int q = 0; q < 8; q++) {
            float4 uq = *(const float4*)(src + q * 256 + uo);
            U[q][0] += uq.x; U[q][1] += uq.y; U[q][2] += uq.z; U[q][3] += uq.w;
        }
    }
    __syncthreads();
    if (w == 2) {
        float* dst = ubuf[0];
#pragma unroll
        for (int q = 0; q < 8; q++) {
            float4 uq = {U[q][0], U[q][1], U[q][2], U[q][3]};
            *(float4*)(dst + q * 256 + uo) = uq;
        }
    }
    __syncthreads();
    if (w == 0) {
        const float* src = ubuf[0];
        float* up = Upart + (size_t)(b * 8 + chunk) * 2048 + uo;
#pragma unroll
        for (int q = 0; q < 8; q++) {
            float4 uq = *(const float4*)(src + q * 256 + uo);
            float4 o = {U[q][0] + uq.x, U[q][1] + uq.y, U[q][2] + uq.z, U[q][3] + uq.w};
            *(float4*)(up + q * 256) = o;
        }
    }
}

// -------- fused slot update v4: 1024 threads, k-split GEMVs, reg-batched weight loads --------
// 256 blocks x 1024 threads; 2 rows per block.
__global__ __launch_bounds__(1024) void slot_fused_kernel(const float* __restrict__ Upart,
                                                          const float* __restrict__ Cpart,
                                                          const float* __restrict__ slotsIn,
                                                          const ushort_t* __restrict__ wg,
                                                          const float* __restrict__ b_ih,
                                                          const float* __restrict__ b_hh,
                                                          const float* __restrict__ ln_mlp_g,
                                                          const float* __restrict__ ln_mlp_b,
                                                          const ushort_t* __restrict__ w1p,
                                                          const float* __restrict__ b1,
                                                          const ushort_t* __restrict__ w2q,
                                                          const float* __restrict__ b2,
                                                          const float* __restrict__ ln_sl_g,
                                                          const float* __restrict__ ln_sl_b,
                                                          const ushort_t* __restrict__ Wqp,
                                                          float* __restrict__ slotsOut,
                                                          float* __restrict__ qp,
                                                          int emit_qp) {
    __shared__ float U_s[2][256], H_s[2][256];
    __shared__ float rsum[2][2][256];
    __shared__ float gpart[2][12][256];   // [kh][mh*6+gate*2+row][c]
    __shared__ float SB_s[2][256], M_s[2][256];
    __shared__ float hid_s[2][512];
    __shared__ float mpart[2][2][512];
    __shared__ float ppart[4][2][256];
    __shared__ float redA[8], redB[8];
    const int t = threadIdx.x;
    const int kh = t >> 9, s9 = t & 511;
    const int rr = s9 >> 8, c = s9 & 255;
    const int lane = t & 63, wvi = t >> 6;
    const int r0 = blockIdx.x * 2;
    const int rg = r0 + rr, bb_ = rg >> 3, q = rg & 7;

    // ---- phase 0: Upart reduce (k-split over partial sets) + normalize ----
    {
        float s = 0.f;
#pragma unroll
        for (int p2 = 0; p2 < 4; p2++)
            s += Upart[(size_t)(bb_ * 8 + kh * 4 + p2) * 2048 + q * 256 + c];
        rsum[kh][rr][c] = s;
    }
    __syncthreads();
    if (kh == 0) {
        int h = c >> 6;
        float C = 0.f;
#pragma unroll
        for (int p2 = 0; p2 < 8; p2++)
            C += Cpart[(size_t)(bb_ * 8 + p2) * 32 + h * 8 + q];
        U_s[rr][c] = (rsum[0][rr][c] + rsum[1][rr][c]) / C;
        H_s[rr][c] = slotsIn[(size_t)rg * 256 + c];
    }
    __syncthreads();

    // ---- GRU GEMV: thread (kh, mh=rr, c); k in [kh*128, kh*128+128) ----
    {
        float ar0, az0, an0;
        if (kh == 0) {
            const float* bias = rr ? b_hh : b_ih;
            ar0 = bias[c]; az0 = bias[256 + c]; an0 = bias[512 + c];
        } else { ar0 = az0 = an0 = 0.f; }
        float ar1 = ar0, az1 = az0, an1 = an0;
        const float (*act)[256] = rr ? H_s : U_s;
        const ushort_t* wp = wg + (size_t)s9 * 4;
        for (int cc = 0; cc < 8; cc++) {
            uint2 wreg[16];
#pragma unroll
            for (int i = 0; i < 16; i++) {
                int k = kh * 128 + cc * 16 + i;
                wreg[i] = *(const uint2*)(wp + (size_t)k * 2048);
            }
#pragma unroll
            for (int i = 0; i < 16; i++) {
                int k = kh * 128 + cc * 16 + i;
                float w0  = bf2f(wreg[i].x & 0xffffu);
                float w1_ = bf2f(wreg[i].x >> 16);
                float w2_ = bf2f(wreg[i].y & 0xffffu);
                float a0 = act[0][k], a1 = act[1][k];
                ar0 += a0 * w0; az0 += a0 * w1_; an0 += a0 * w2_;
                ar1 += a1 * w0; az1 += a1 * w1_; an1 += a1 * w2_;
            }
        }
        gpart[kh][rr * 6 + 0][c] = ar0; gpart[kh][rr * 6 + 1][c] = ar1;
        gpart[kh][rr * 6 + 2][c] = az0; gpart[kh][rr * 6 + 3][c] = az1;
        gpart[kh][rr * 6 + 4][c] = an0; gpart[kh][rr * 6 + 5][c] = an1;
    }
    __syncthreads();

    // ---- gates + LN(mlp): kh==0 threads (8 full waves) ----
    float sb = 0.f;
    if (kh == 0) {
        float xr = gpart[0][0 + rr][c] + gpart[1][0 + rr][c];
        float xz = gpart[0][2 + rr][c] + gpart[1][2 + rr][c];
        float xn = gpart[0][4 + rr][c] + gpart[1][4 + rr][c];
        float hr = gpart[0][6 + rr][c] + gpart[1][6 + rr][c];
        float hz = gpart[0][8 + rr][c] + gpart[1][8 + rr][c];
        float hn = gpart[0][10 + rr][c] + gpart[1][10 + rr][c];
        float rg_ = 1.f / (1.f + __expf(-(xr + hr)));
        float z   = 1.f / (1.f + __expf(-(xz + hz)));
        float nn  = tanhf(xn + rg_ * hn);
        sb = (1.f - z) * nn + z * H_s[rr][c];
        SB_s[rr][c] = sb;
        float s1 = wred_sum(sb), s2 = wred_sum(sb * sb);
        if (lane == 0) { redA[wvi] = s1; redB[wvi] = s2; }
    }
    __syncthreads();
    if (kh == 0) {
        int base = rr * 4;
        float m  = (redA[base] + redA[base + 1] + redA[base + 2] + redA[base + 3]) * (1.f / 256.f);
        float e2 = (redB[base] + redB[base + 1] + redB[base + 2] + redB[base + 3]) * (1.f / 256.f);
        float rst = rsqrtf(e2 - m * m + LNEPS);
        M_s[rr][c] = (sb - m) * rst * ln_mlp_g[c] + ln_mlp_b[c];
    }
    __syncthreads();

    // ---- MLP1: thread (kh, col j=s9); k4 in [kh*32, kh*32+32) ----
    {
        float h10 = 0.f, h11 = 0.f;
        const ushort_t* wp = w1p + (size_t)s9 * 4;
        for (int cc = 0; cc < 2; cc++) {
            uint2 wreg[16];
#pragma unroll
            for (int i = 0; i < 16; i++) {
                int k4 = kh * 32 + cc * 16 + i;
                wreg[i] = *(const uint2*)(wp + (size_t)k4 * 2048);
            }
#pragma unroll
            for (int i = 0; i < 16; i++) {
                int k4 = kh * 32 + cc * 16 + i;
                float wA[4] = {bf2f(wreg[i].x & 0xffffu), bf2f(wreg[i].x >> 16),
                               bf2f(wreg[i].y & 0xffffu), bf2f(wreg[i].y >> 16)};
#pragma unroll
                for (int ii = 0; ii < 4; ii++) {
                    int k = k4 * 4 + ii;
                    h10 += M_s[0][k] * wA[ii];
                    h11 += M_s[1][k] * wA[ii];
                }
            }
        }
        mpart[kh][0][s9] = h10;
        mpart[kh][1][s9] = h11;
    }
    __syncthreads();
    if (kh == 0) {
        float bb1 = b1[s9];
        hid_s[0][s9] = fmaxf(mpart[0][0][s9] + mpart[1][0][s9] + bb1, 0.f);
        hid_s[1][s9] = fmaxf(mpart[0][1][s9] + mpart[1][1][s9] + bb1, 0.f);
    }
    __syncthreads();

    // ---- MLP2: thread (q2=kh*2+rr, c); k4g in [q2*32, q2*32+32) ----
    {
        int q2 = kh * 2 + rr;
        float p0 = 0.f, p1 = 0.f;
        const ushort_t* wp = w2q + (size_t)c * 4;
        for (int cc = 0; cc < 2; cc++) {
            uint2 wreg[16];
#pragma unroll
            for (int i = 0; i < 16; i++) {
                int k4g = q2 * 32 + cc * 16 + i;
                wreg[i] = *(const uint2*)(wp + (size_t)k4g * 1024);
            }
#pragma unroll
            for (int i = 0; i < 16; i++) {
                int k4g = q2 * 32 + cc * 16 + i;
                float wA[4] = {bf2f(wreg[i].x & 0xffffu), bf2f(wreg[i].x >> 16),
                               bf2f(wreg[i].y & 0xffffu), bf2f(wreg[i].y >> 16)};
#pragma unroll
                for (int ii = 0; ii < 4; ii++) {
                    int k = k4g * 4 + ii;
                    p0 += hid_s[0][k] * wA[ii];
                    p1 += hid_s[1][k] * wA[ii];
                }
            }
        }
        ppart[q2][0][c] = p0;
        ppart[q2][1][c] = p1;
    }
    __syncthreads();
    float outv = 0.f;
    if (kh == 0) {
        outv = ppart[0][rr][c] + ppart[1][rr][c] + ppart[2][rr][c] + ppart[3][rr][c]
             + b2[c] + SB_s[rr][c];
        slotsOut[(size_t)rg * 256 + c] = outv;
    }

    if (emit_qp) {
        __syncthreads();
        if (kh == 0) {
            float s1 = wred_sum(outv), s2 = wred_sum(outv * outv);
            if (lane == 0) { redA[wvi] = s1; redB[wvi] = s2; }
        }
        __syncthreads();
        if (kh == 0) {
            int base = rr * 4;
            float m  = (redA[base] + redA[base + 1] + redA[base + 2] + redA[base + 3]) * (1.f / 256.f);
            float e2 = (redB[base] + redB[base + 1] + redB[base + 2] + redB[base + 3]) * (1.f / 256.f);
            float rst = rsqrtf(e2 - m * m + LNEPS);
            M_s[rr][c] = (outv - m) * rst * ln_sl_g[c] + ln_sl_b[c];
        }
        __syncthreads();
        {
            int q2 = kh * 2 + rr;
            float p0 = 0.f, p1 = 0.f;
            const ushort_t* wp = Wqp + (size_t)c * 4;
            uint2 wreg[16];
#pragma unroll
            for (int i = 0; i < 16; i++) {
                int k4g = q2 * 16 + i;
                wreg[i] = *(const uint2*)(wp + (size_t)k4g * 1024);
            }
#pragma unroll
            for (int i = 0; i < 16; i++) {
                int k4g = q2 * 16 + i;
                float wA[4] = {bf2f(wreg[i].x & 0xffffu), bf2f(wreg[i].x >> 16),
                               bf2f(wreg[i].y & 0xffffu), bf2f(wreg[i].y >> 16)};
#pragma unroll
                for (int ii = 0; ii < 4; ii++) {
                    int k = k4g * 4 + ii;
                    p0 += M_s[0][k] * wA[ii];
                    p1 += M_s[1][k] * wA[ii];
                }
            }
            ppart[q2][0][c] = p0;
            ppart[q2][1][c] = p1;
        }
        __syncthreads();
        if (kh == 0) {
            float qv = ppart[0][rr][c] + ppart[1][rr][c] + ppart[2][rr][c] + ppart[3][rr][c];
            qp[(size_t)bb_ * 2048 + (c >> 6) * 512 + q * 64 + (c & 63)] = qv;
        }
    }
}

// -------- host --------
extern "C" void kernel_launch(void* const* d_in, const int* in_sizes, int n_in,
                              void* d_out, int out_size, void* d_ws, size_t ws_size,
                              hipStream_t stream) {
    const float* inputs   = (const float*)d_in[0];
    const float* slots0   = (const float*)d_in[1];
    const float* ln_in_g  = (const float*)d_in[2];
    const float* ln_in_b  = (const float*)d_in[3];
    const float* ln_sl_g  = (const float*)d_in[4];
    const float* ln_sl_b  = (const float*)d_in[5];
    const float* ln_mlp_g = (const float*)d_in[6];
    const float* ln_mlp_b = (const float*)d_in[7];
    const float* Wq       = (const float*)d_in[8];
    const float* Wk       = (const float*)d_in[9];
    const float* Wv       = (const float*)d_in[10];
    const float* w_ih     = (const float*)d_in[11];
    const float* w_hh     = (const float*)d_in[12];
    const float* b_ih     = (const float*)d_in[13];
    const float* b_hh     = (const float*)d_in[14];
    const float* w1       = (const float*)d_in[15];
    const float* b1       = (const float*)d_in[16];
    const float* w2       = (const float*)d_in[17];
    const float* b2       = (const float*)d_in[18];

    float* out_slots = (float*)d_out;
    float* out_vis   = (float*)d_out + 64 * 8 * 256;

    char* p = (char*)d_ws;
    auto carve = [&](size_t bytes) {
        void* r = (void*)p;
        p += (bytes + 255) & ~(size_t)255;
        return r;
    };
    ushort_t* kv   = (ushort_t*)carve((size_t)65536 * 512 * 2);   // 64 MB
    ushort_t* Wt   = (ushort_t*)carve((size_t)512 * 256 * 2);
    ushort_t* Wtp  = (ushort_t*)carve((size_t)512 * 256 * 2);
    ushort_t* wg   = (ushort_t*)carve((size_t)256 * 512 * 4 * 2);
    ushort_t* w1p  = (ushort_t*)carve((size_t)64 * 512 * 4 * 2);
    ushort_t* w2q  = (ushort_t*)carve((size_t)128 * 256 * 4 * 2);
    ushort_t* Wqp  = (ushort_t*)carve((size_t)64 * 256 * 4 * 2);
    float* qp      = (float*)carve((size_t)64 * 2048 * 4);
    float* Upart   = (float*)carve((size_t)64 * 8 * 2048 * 4);    // 4 MB
    float* Cpart   = (float*)carve((size_t)64 * 8 * 32 * 4);
    float* slotsA  = (float*)carve((size_t)512 * 256 * 4);

    prepack_w_kernel<<<512, 256, 0, stream>>>(Wk, Wv, Wt);
    prepack_wtp_kernel<<<64, 256, 0, stream>>>(Wt, Wtp);
    prepack_slotw_kernel<<<dim3(256, 4), 512, 0, stream>>>(w_ih, w_hh, w1, w2, Wq,
                                                           wg, w1p, w2q, Wqp);
    kvproj_mfma_kernel<<<1024, 512, 0, stream>>>(inputs, ln_in_g, ln_in_b, Wtp, kv);
    qproj_kernel<<<512, 256, 0, stream>>>(slots0, ln_sl_g, ln_sl_b, Wq, qp);

    for (int it = 0; it < 3; ++it) {
        attn_fused_kernel<<<dim3(8, 64), 256, 0, stream>>>(kv, qp, Upart, Cpart, out_vis,
                                                           (it == 2) ? 1 : 0);
        slot_fused_kernel<<<256, 1024, 0, stream>>>(
            Upart, Cpart, (it == 0) ? slots0 : slotsA,
            wg, b_ih, b_hh, ln_mlp_g, ln_mlp_b, w1p, b1, w2q, b2,
            ln_sl_g, ln_sl_b, Wqp,
            (it == 2) ? out_slots : slotsA, qp, (it < 2) ? 1 : 0);
    }
}

// Round 13
// 207.557 us; speedup vs baseline: 1.4506x; 1.0153x over previous
//
#include <hip/hip_runtime.h>
#include <hip/hip_bf16.h>
#include <math.h>

#define EPS_  1e-8f
#define LNEPS 1e-5f

typedef __attribute__((ext_vector_type(8))) short   short8;
typedef __attribute__((ext_vector_type(8))) __bf16  bf16x8;
typedef __attribute__((ext_vector_type(4))) float   f32x4;
typedef unsigned short ushort_t;

__device__ __forceinline__ float bf2f(unsigned int u) { return __uint_as_float(u << 16); }
__device__ __forceinline__ unsigned short f2bf(float f) {
    unsigned int u = __float_as_uint(f);
    u += 0x7fff + ((u >> 16) & 1);
    return (unsigned short)(u >> 16);
}
__device__ __forceinline__ unsigned int cvt_pk_bf16(float lo, float hi) {
    unsigned int r;
    asm("v_cvt_pk_bf16_f32 %0, %1, %2" : "=v"(r) : "v"(lo), "v"(hi));
    return r;
}
__device__ __forceinline__ f32x4 mfma_bf16(short8 a, short8 b, f32x4 c) {
    union U { short8 s; bf16x8 b; };
    U ua, ub; ua.s = a; ub.s = b;
    return __builtin_amdgcn_mfma_f32_16x16x32_bf16(ua.b, ub.b, c, 0, 0, 0);
}
__device__ __forceinline__ float wred_sum(float v) {
#pragma unroll
    for (int off = 32; off > 0; off >>= 1) v += __shfl_xor(v, off);
    return v;
}

// -------- prepack Wk/Wv -> Wt[n][k] bf16 (k pre-scaled 0.125) --------
__global__ __launch_bounds__(256) void prepack_w_kernel(const float* __restrict__ Wk,
                                                        const float* __restrict__ Wv,
                                                        ushort_t* __restrict__ Wt) {
    int n = blockIdx.x;
    int k = threadIdx.x;
    float v = (n < 256) ? Wk[(size_t)k * 256 + n] * 0.125f : Wv[(size_t)k * 256 + (n - 256)];
    Wt[(size_t)n * 256 + k] = f2bf(v);
}

// -------- prepack Wt -> Wtp: per (wave,step,ni) 1KB block, lane-contiguous MFMA B-frags ----
__global__ __launch_bounds__(256) void prepack_wtp_kernel(const ushort_t* __restrict__ Wt,
                                                          ushort_t* __restrict__ Wtp) {
    int bs = blockIdx.x;              // wv*8+s, 0..63
    int wv = bs >> 3, s = bs & 7;
    int ni = threadIdx.x >> 6, l = threadIdx.x & 63;
    int n  = wv * 64 + ni * 16 + (l & 15);
    int k0 = s * 32 + (l >> 4) * 8;
    short8 v = *(const short8*)(Wt + (size_t)n * 256 + k0);
    *(short8*)(Wtp + ((size_t)bs * 4 + ni) * 512 + l * 8) = v;
}

// -------- prepack slot-chain weights to bf16 interleaved layouts --------
__global__ __launch_bounds__(512) void prepack_slotw_kernel(const float* __restrict__ w_ih,
                                                            const float* __restrict__ w_hh,
                                                            const float* __restrict__ w1,
                                                            const float* __restrict__ w2,
                                                            const float* __restrict__ Wq,
                                                            ushort_t* __restrict__ wg,
                                                            ushort_t* __restrict__ w1p,
                                                            ushort_t* __restrict__ w2q,
                                                            ushort_t* __restrict__ Wqp) {
    int t = threadIdx.x, bid = blockIdx.x, sec = blockIdx.y;
    if (sec == 0) {
        if (bid < 256) {
            int k = bid, c = t & 255;
            const float* src = (t >> 8) ? w_hh : w_ih;
            size_t o = ((size_t)k * 512 + t) * 4;
            wg[o + 0] = f2bf(src[(size_t)(0 * 256 + c) * 256 + k]);
            wg[o + 1] = f2bf(src[(size_t)(1 * 256 + c) * 256 + k]);
            wg[o + 2] = f2bf(src[(size_t)(2 * 256 + c) * 256 + k]);
            wg[o + 3] = 0;
        }
    } else if (sec == 1) {
        if (bid < 64) {
            size_t o = ((size_t)bid * 512 + t) * 4;
#pragma unroll
            for (int i = 0; i < 4; i++) w1p[o + i] = f2bf(w1[(size_t)(bid * 4 + i) * 512 + t]);
        }
    } else if (sec == 2) {
        if (bid < 64) {
            int k4g = bid * 2 + (t >> 8), c = t & 255;
            size_t o = ((size_t)k4g * 256 + c) * 4;
#pragma unroll
            for (int i = 0; i < 4; i++) w2q[o + i] = f2bf(w2[(size_t)(k4g * 4 + i) * 256 + c]);
        }
    } else {
        if (bid < 32) {
            int k4g = bid * 2 + (t >> 8), c = t & 255;
            size_t o = ((size_t)k4g * 256 + c) * 4;
#pragma unroll
            for (int i = 0; i < 4; i++) Wqp[o + i] = f2bf(Wq[(size_t)(k4g * 4 + i) * 256 + c]);
        }
    }
}

// -------- KV projection v7 (round 10, unchanged) --------
__global__ __launch_bounds__(512, 4) void kvproj_mfma_kernel(const float* __restrict__ in,
                                                             const float* __restrict__ g,
                                                             const float* __restrict__ bb,
                                                             const ushort_t* __restrict__ Wtp,
                                                             ushort_t* __restrict__ kvout) {
    __shared__ __align__(16) ushort_t As[64 * 256];
    const int tid = threadIdx.x;
    const int wv = tid >> 6, l = tid & 63;
    const int kc = l >> 4, lr = l & 15;
    const int m0 = blockIdx.x * 64;

    float4 g4 = *(const float4*)(g + l * 4);
    float4 b4 = *(const float4*)(bb + l * 4);
    float4 xv[8];
#pragma unroll
    for (int i = 0; i < 8; i++)
        xv[i] = *(const float4*)(in + (size_t)(m0 + i * 8 + wv) * 256 + l * 4);
#pragma unroll
    for (int i = 0; i < 8; i++) {
        float s1 = xv[i].x + xv[i].y + xv[i].z + xv[i].w;
        float s2 = xv[i].x * xv[i].x + xv[i].y * xv[i].y + xv[i].z * xv[i].z + xv[i].w * xv[i].w;
        s1 = wred_sum(s1);
        s2 = wred_sum(s2);
        float m = s1 * (1.0f / 256.0f);
        float r = rsqrtf(s2 * (1.0f / 256.0f) - m * m + LNEPS);
        float v0 = (xv[i].x - m) * r * g4.x + b4.x;
        float v1 = (xv[i].y - m) * r * g4.y + b4.y;
        float v2 = (xv[i].z - m) * r * g4.z + b4.z;
        float v3 = (xv[i].w - m) * r * g4.w + b4.w;
        uint2 pk = {cvt_pk_bf16(v0, v1), cvt_pk_bf16(v2, v3)};
        int row = i * 8 + wv;
        *(uint2*)&As[row * 256 + (((l >> 1) ^ (row & 15)) * 8) + (l & 1) * 4] = pk;
    }
    __syncthreads();

    f32x4 zero = {0.f, 0.f, 0.f, 0.f};
    f32x4 acc[4][4];
#pragma unroll
    for (int i = 0; i < 4; i++)
#pragma unroll
        for (int jj = 0; jj < 4; jj++) acc[i][jj] = zero;

    const ushort_t* wbase = Wtp + ((size_t)(wv * 8) * 4) * 512 + l * 8;
#pragma unroll
    for (int s = 0; s < 8; s++) {
        short8 bfr[4];
        const ushort_t* wpb = wbase + (size_t)s * 4 * 512;
#pragma unroll
        for (int ni = 0; ni < 4; ni++) bfr[ni] = *(const short8*)(wpb + ni * 512);
        short8 af[4];
#pragma unroll
        for (int mi = 0; mi < 4; mi++) {
            int r2 = lr + mi * 16;
            int c = s * 4 + kc;
            af[mi] = *(const short8*)&As[r2 * 256 + ((c ^ (r2 & 15)) * 8)];
        }
#pragma unroll
        for (int mi = 0; mi < 4; mi++)
#pragma unroll
            for (int ni = 0; ni < 4; ni++)
                acc[mi][ni] = mfma_bf16(af[mi], bfr[ni], acc[mi][ni]);
    }

    const int odd = l & 1;
    const int colbase = wv * 64;
#pragma unroll
    for (int mi = 0; mi < 4; mi++)
#pragma unroll
        for (int ni = 0; ni < 4; ni++) {
            float s0 = odd ? acc[mi][ni][0] : acc[mi][ni][2];
            float s1_ = odd ? acc[mi][ni][1] : acc[mi][ni][3];
            float r0 = __shfl_xor(s0, 1);
            float r1_ = __shfl_xor(s1_, 1);
            int col0 = colbase + ni * 16 + (lr & ~1);
            unsigned int packA, packB;
            int rowA;
            if (!odd) {
                packA = cvt_pk_bf16(acc[mi][ni][0], r0);
                packB = cvt_pk_bf16(acc[mi][ni][1], r1_);
                rowA = m0 + mi * 16 + kc * 4 + 0;
            } else {
                packA = cvt_pk_bf16(r0, acc[mi][ni][2]);
                packB = cvt_pk_bf16(r1_, acc[mi][ni][3]);
                rowA = m0 + mi * 16 + kc * 4 + 2;
            }
            *(unsigned int*)(kvout + (size_t)rowA * 512 + col0) = packA;
            *(unsigned int*)(kvout + (size_t)(rowA + 1) * 512 + col0) = packB;
        }
}

// -------- initial slot LN + q projection (once). grid 512 x 256 --------
__global__ __launch_bounds__(256) void qproj_kernel(const float* __restrict__ slots,
                                                    const float* __restrict__ g,
                                                    const float* __restrict__ bvec,
                                                    const float* __restrict__ Wq,
                                                    float* __restrict__ qp) {
    int row = blockIdx.x;
    int tid = threadIdx.x;
    __shared__ float s_s[256];
    __shared__ float red[8];
    float x = slots[(size_t)row * 256 + tid];
    float s1 = wred_sum(x);
    float s2 = wred_sum(x * x);
    if ((tid & 63) == 0) { red[tid >> 6] = s1; red[4 + (tid >> 6)] = s2; }
    __syncthreads();
    float m  = (red[0] + red[1] + red[2] + red[3]) * (1.0f / 256.0f);
    float e2 = (red[4] + red[5] + red[6] + red[7]) * (1.0f / 256.0f);
    float rst = rsqrtf(e2 - m * m + LNEPS);
    s_s[tid] = (x - m) * rst * g[tid] + bvec[tid];
    __syncthreads();
    float acc = 0.f;
#pragma unroll 4
    for (int d = 0; d < 256; d++) acc += s_s[d] * Wq[(size_t)d * 256 + tid];
    int b = row >> 3, q = row & 7;
    qp[((size_t)(b * 4 + (tid >> 6)) * 8 + q) * 64 + (tid & 63)] = acc;
}

// -------- fused attention v5: MFMA logits + softmax + pipelined V accum + U reduce --------
// grid (8 chunks of 128 tokens, 64 b) x 256 threads (4 waves).
__global__ __launch_bounds__(256) void attn_fused_kernel(const ushort_t* __restrict__ kv,
                                                         const float* __restrict__ qp,
                                                         float* __restrict__ Upart,
                                                         float* __restrict__ Cpart,
                                                         float* __restrict__ vis,
                                                         int write_vis) {
    int b = blockIdx.y;
    int chunk = blockIdx.x;
    int tid = threadIdx.x;
    __shared__ __align__(16) ushort_t qfrag[16 * 512];  // 16 KB
    __shared__ float att[128][32];                      // 16 KB
    __shared__ float ubuf[2][2048];                     // 16 KB
    __shared__ float cred[8][32];

    {
        const float* qb_ = qp + (size_t)b * 2048;
#pragma unroll
        for (int snt = 0; snt < 16; snt++) {
            int s = snt >> 1, nt = snt & 1;
#pragma unroll
            for (int rep = 0; rep < 2; rep++) {
                int idx = tid + rep * 256;  // 0..511
                int k  = s * 32 + ((idx >> 7) << 3) + (idx & 7);
                int hq = nt * 16 + ((idx >> 3) & 15);
                float v = ((k >> 6) == (hq >> 3))
                              ? qb_[(hq >> 3) * 512 + (hq & 7) * 64 + (k & 63)] : 0.f;
                qfrag[snt * 512 + idx] = f2bf(v);
            }
        }
    }
    __syncthreads();

    const int w = tid >> 6, l = tid & 63;
    const int lr = l & 15, kc8 = (l >> 4) * 8;
    const int h_u = l >> 4, d4 = l & 15;
    const int uo = h_u * 64 + d4 * 4;
    const ushort_t* vbase = kv + (size_t)(b * 1024 + chunk * 128 + w * 32) * 512 + 256 + uo;

    short8 qb2[2][8];
#pragma unroll
    for (int s = 0; s < 8; s++) {
        qb2[0][s] = *(const short8*)&qfrag[(s * 2 + 0) * 512 + l * 8];
        qb2[1][s] = *(const short8*)&qfrag[(s * 2 + 1) * 512 + l * 8];
    }
    f32x4 zero = {0.f, 0.f, 0.f, 0.f};
#pragma unroll
    for (int mi_loc = 0; mi_loc < 2; mi_loc++) {
        int mi = w * 2 + mi_loc;
        f32x4 a0 = zero, a1 = zero;
        const ushort_t* abase = kv + (size_t)(b * 1024 + chunk * 128 + mi * 16 + lr) * 512 + kc8;
#pragma unroll
        for (int s = 0; s < 8; s++) {
            short8 af = *(const short8*)(abase + s * 32);
            a0 = mfma_bf16(af, qb2[0][s], a0);
            a1 = mfma_bf16(af, qb2[1][s], a1);
        }
        int row0 = mi * 16 + (l >> 4) * 4;
#pragma unroll
        for (int r = 0; r < 4; r++) {
            att[row0 + r][lr]      = a0[r];
            att[row0 + r][16 + lr] = a1[r];
        }
    }
    // ---- T14: issue first V chunk loads before softmax barriers ----
    uint2 vpre[8];
#pragma unroll
    for (int i = 0; i < 8; i++)
        vpre[i] = *(const uint2*)(vbase + (size_t)i * 512);
    __syncthreads();

    {
        int token = tid >> 1, half = tid & 1;
        float v[16];
        float mx = -3.4e38f;
#pragma unroll
        for (int j = 0; j < 16; j++) { v[j] = att[token][half * 16 + j]; mx = fmaxf(mx, v[j]); }
        mx = fmaxf(mx, __shfl_xor(mx, 1));
        float sm = 0.f;
#pragma unroll
        for (int j = 0; j < 16; j++) { v[j] = __expf(v[j] - mx); sm += v[j]; }
        sm += __shfl_xor(sm, 1);
        float inv = 1.0f / sm;
#pragma unroll
        for (int j = 0; j < 16; j++) { v[j] *= inv; att[token][half * 16 + j] = v[j] + EPS_; }
        if (write_vis) {
#pragma unroll
            for (int q = 0; q < 8; q++) {
                float pv = v[q] + v[q + 8];
                float pf = pv + __shfl_xor(pv, 1);
                if (half == 0) vis[(size_t)(b * 8 + q) * 1024 + chunk * 128 + token] = pf;
            }
        }
    }
    __syncthreads();

    {
        int hq2 = tid & 31, grp = tid >> 5;
        float s = 0.f;
#pragma unroll
        for (int i = 0; i < 16; i++) s += att[grp * 16 + i][hq2];
        cred[grp][hq2] = s;
    }
    __syncthreads();
    if (tid < 32) {
        float s = 0.f;
#pragma unroll
        for (int g2 = 0; g2 < 8; g2++) s += cred[g2][tid];
        Cpart[(size_t)(b * 8 + chunk) * 32 + tid] = s;
    }

    // ---- phase B: pipelined over 4 chunks of 8 tokens ----
    float U[8][4];
#pragma unroll
    for (int q = 0; q < 8; q++)
#pragma unroll
        for (int d = 0; d < 4; d++) U[q][d] = 0.f;
    for (int c4 = 0; c4 < 4; ++c4) {
        uint2 vnx[8];
        if (c4 < 3) {
#pragma unroll
            for (int i = 0; i < 8; i++)
                vnx[i] = *(const uint2*)(vbase + (size_t)((c4 + 1) * 8 + i) * 512);
        }
#pragma unroll
        for (int i2 = 0; i2 < 8; i2++) {
            uint2 vp = vpre[i2];
            float v0 = bf2f(vp.x & 0xffffu), v1 = bf2f(vp.x >> 16);
            float v2 = bf2f(vp.y & 0xffffu), v3 = bf2f(vp.y >> 16);
            const float* arow = &att[w * 32 + c4 * 8 + i2][h_u * 8];
            float4 a01 = *(const float4*)(arow);
            float4 a23 = *(const float4*)(arow + 4);
            float aq[8] = {a01.x, a01.y, a01.z, a01.w, a23.x, a23.y, a23.z, a23.w};
#pragma unroll
            for (int q = 0; q < 8; q++) {
                U[q][0] += aq[q] * v0; U[q][1] += aq[q] * v1;
                U[q][2] += aq[q] * v2; U[q][3] += aq[q] * v3;
            }
        }
        if (c4 < 3) {
#pragma unroll
            for (int i = 0; i < 8; i++) vpre[i] = vnx[i];
        }
    }
    if (w & 1) {
        float* dst = ubuf[w >> 1];
#pragma unroll
        for (int q = 0; q < 8; q++) {
            float4 uq = {U[q][0], U[q][1], U[q][2], U[q][3]};
            *(float4*)(dst + q * 256 + uo) = uq;
        }
    }
    __syncthreads();
    if (!(w & 1)) {
        const float* src = ubuf[w >> 1];
#pragma unroll
        for (int q = 0; q < 8; q++) {
            float4 uq = *(const float4*)(src + q * 256 + uo);
            U[q][0] += uq.x; U[q][1] += uq.y; U[q][2] += uq.z; U[q][3] += uq.w;
        }
    }
    __syncthreads();
    if (w == 2) {
        float* dst = ubuf[0];
#pragma unroll
        for (int q = 0; q < 8; q++) {
            float4 uq = {U[q][0], U[q][1], U[q][2], U[q][3]};
            *(float4*)(dst + q * 256 + uo) = uq;
        }
    }
    __syncthreads();
    if (w == 0) {
        const float* src = ubuf[0];
        float* up = Upart + (size_t)(b * 8 + chunk) * 2048 + uo;
#pragma unroll
        for (int q = 0; q < 8; q++) {
            float4 uq = *(const float4*)(src + q * 256 + uo);
            float4 o = {U[q][0] + uq.x, U[q][1] + uq.y, U[q][2] + uq.z, U[q][3] + uq.w};
            *(float4*)(up + q * 256) = o;
        }
    }
}

// -------- fused slot update v4 (bf16 weights, round 10): 1024 threads, k-split GEMVs --------
// 256 blocks x 1024 threads; 2 rows per block.
__global__ __launch_bounds__(1024) void slot_fused_kernel(const float* __restrict__ Upart,
                                                          const float* __restrict__ Cpart,
                                                          const float* __restrict__ slotsIn,
                                                          const ushort_t* __restrict__ wg,
                                                          const float* __restrict__ b_ih,
                                                          const float* __restrict__ b_hh,
                                                          const float* __restrict__ ln_mlp_g,
                                                          const float* __restrict__ ln_mlp_b,
                                                          const ushort_t* __restrict__ w1p,
                                                          const float* __restrict__ b1,
                                                          const ushort_t* __restrict__ w2q,
                                                          const float* __restrict__ b2,
                                                          const float* __restrict__ ln_sl_g,
                                                          const float* __restrict__ ln_sl_b,
                                                          const ushort_t* __restrict__ Wqp,
                                                          float* __restrict__ slotsOut,
                                                          float* __restrict__ qp,
                                                          int emit_qp) {
    __shared__ float U_s[2][256], H_s[2][256];
    __shared__ float rsum[2][2][256];
    __shared__ float gpart[2][12][256];
    __shared__ float SB_s[2][256], M_s[2][256];
    __shared__ float hid_s[2][512];
    __shared__ float mpart[2][2][512];
    __shared__ float ppart[4][2][256];
    __shared__ float redA[8], redB[8];
    const int t = threadIdx.x;
    const int kh = t >> 9, s9 = t & 511;
    const int rr = s9 >> 8, c = s9 & 255;
    const int lane = t & 63, wvi = t >> 6;
    const int r0 = blockIdx.x * 2;
    const int rg = r0 + rr, bb_ = rg >> 3, q = rg & 7;

    {
        float s = 0.f;
#pragma unroll
        for (int p2 = 0; p2 < 4; p2++)
            s += Upart[(size_t)(bb_ * 8 + kh * 4 + p2) * 2048 + q * 256 + c];
        rsum[kh][rr][c] = s;
    }
    __syncthreads();
    if (kh == 0) {
        int h = c >> 6;
        float C = 0.f;
#pragma unroll
        for (int p2 = 0; p2 < 8; p2++)
            C += Cpart[(size_t)(bb_ * 8 + p2) * 32 + h * 8 + q];
        U_s[rr][c] = (rsum[0][rr][c] + rsum[1][rr][c]) / C;
        H_s[rr][c] = slotsIn[(size_t)rg * 256 + c];
    }
    __syncthreads();

    {
        float ar0, az0, an0;
        if (kh == 0) {
            const float* bias = rr ? b_hh : b_ih;
            ar0 = bias[c]; az0 = bias[256 + c]; an0 = bias[512 + c];
        } else { ar0 = az0 = an0 = 0.f; }
        float ar1 = ar0, az1 = az0, an1 = an0;
        const float (*act)[256] = rr ? H_s : U_s;
        const ushort_t* wp = wg + (size_t)s9 * 4;
        for (int cc = 0; cc < 8; cc++) {
            uint2 wreg[16];
#pragma unroll
            for (int i = 0; i < 16; i++) {
                int k = kh * 128 + cc * 16 + i;
                wreg[i] = *(const uint2*)(wp + (size_t)k * 2048);
            }
#pragma unroll
            for (int i = 0; i < 16; i++) {
                int k = kh * 128 + cc * 16 + i;
                float w0  = bf2f(wreg[i].x & 0xffffu);
                float w1_ = bf2f(wreg[i].x >> 16);
                float w2_ = bf2f(wreg[i].y & 0xffffu);
                float a0 = act[0][k], a1 = act[1][k];
                ar0 += a0 * w0; az0 += a0 * w1_; an0 += a0 * w2_;
                ar1 += a1 * w0; az1 += a1 * w1_; an1 += a1 * w2_;
            }
        }
        gpart[kh][rr * 6 + 0][c] = ar0; gpart[kh][rr * 6 + 1][c] = ar1;
        gpart[kh][rr * 6 + 2][c] = az0; gpart[kh][rr * 6 + 3][c] = az1;
        gpart[kh][rr * 6 + 4][c] = an0; gpart[kh][rr * 6 + 5][c] = an1;
    }
    __syncthreads();

    float sb = 0.f;
    if (kh == 0) {
        float xr = gpart[0][0 + rr][c] + gpart[1][0 + rr][c];
        float xz = gpart[0][2 + rr][c] + gpart[1][2 + rr][c];
        float xn = gpart[0][4 + rr][c] + gpart[1][4 + rr][c];
        float hr = gpart[0][6 + rr][c] + gpart[1][6 + rr][c];
        float hz = gpart[0][8 + rr][c] + gpart[1][8 + rr][c];
        float hn = gpart[0][10 + rr][c] + gpart[1][10 + rr][c];
        float rg_ = 1.f / (1.f + __expf(-(xr + hr)));
        float z   = 1.f / (1.f + __expf(-(xz + hz)));
        float nn  = tanhf(xn + rg_ * hn);
        sb = (1.f - z) * nn + z * H_s[rr][c];
        SB_s[rr][c] = sb;
        float s1 = wred_sum(sb), s2 = wred_sum(sb * sb);
        if (lane == 0) { redA[wvi] = s1; redB[wvi] = s2; }
    }
    __syncthreads();
    if (kh == 0) {
        int base = rr * 4;
        float m  = (redA[base] + redA[base + 1] + redA[base + 2] + redA[base + 3]) * (1.f / 256.f);
        float e2 = (redB[base] + redB[base + 1] + redB[base + 2] + redB[base + 3]) * (1.f / 256.f);
        float rst = rsqrtf(e2 - m * m + LNEPS);
        M_s[rr][c] = (sb - m) * rst * ln_mlp_g[c] + ln_mlp_b[c];
    }
    __syncthreads();

    {
        float h10 = 0.f, h11 = 0.f;
        const ushort_t* wp = w1p + (size_t)s9 * 4;
        for (int cc = 0; cc < 2; cc++) {
            uint2 wreg[16];
#pragma unroll
            for (int i = 0; i < 16; i++) {
                int k4 = kh * 32 + cc * 16 + i;
                wreg[i] = *(const uint2*)(wp + (size_t)k4 * 2048);
            }
#pragma unroll
            for (int i = 0; i < 16; i++) {
                int k4 = kh * 32 + cc * 16 + i;
                float wA[4] = {bf2f(wreg[i].x & 0xffffu), bf2f(wreg[i].x >> 16),
                               bf2f(wreg[i].y & 0xffffu), bf2f(wreg[i].y >> 16)};
#pragma unroll
                for (int ii = 0; ii < 4; ii++) {
                    int k = k4 * 4 + ii;
                    h10 += M_s[0][k] * wA[ii];
                    h11 += M_s[1][k] * wA[ii];
                }
            }
        }
        mpart[kh][0][s9] = h10;
        mpart[kh][1][s9] = h11;
    }
    __syncthreads();
    if (kh == 0) {
        float bb1 = b1[s9];
        hid_s[0][s9] = fmaxf(mpart[0][0][s9] + mpart[1][0][s9] + bb1, 0.f);
        hid_s[1][s9] = fmaxf(mpart[0][1][s9] + mpart[1][1][s9] + bb1, 0.f);
    }
    __syncthreads();

    {
        int q2 = kh * 2 + rr;
        float p0 = 0.f, p1 = 0.f;
        const ushort_t* wp = w2q + (size_t)c * 4;
        for (int cc = 0; cc < 2; cc++) {
            uint2 wreg[16];
#pragma unroll
            for (int i = 0; i < 16; i++) {
                int k4g = q2 * 32 + cc * 16 + i;
                wreg[i] = *(const uint2*)(wp + (size_t)k4g * 1024);
            }
#pragma unroll
            for (int i = 0; i < 16; i++) {
                int k4g = q2 * 32 + cc * 16 + i;
                float wA[4] = {bf2f(wreg[i].x & 0xffffu), bf2f(wreg[i].x >> 16),
                               bf2f(wreg[i].y & 0xffffu), bf2f(wreg[i].y >> 16)};
#pragma unroll
                for (int ii = 0; ii < 4; ii++) {
                    int k = k4g * 4 + ii;
                    p0 += hid_s[0][k] * wA[ii];
                    p1 += hid_s[1][k] * wA[ii];
                }
            }
        }
        ppart[q2][0][c] = p0;
        ppart[q2][1][c] = p1;
    }
    __syncthreads();
    float outv = 0.f;
    if (kh == 0) {
        outv = ppart[0][rr][c] + ppart[1][rr][c] + ppart[2][rr][c] + ppart[3][rr][c]
             + b2[c] + SB_s[rr][c];
        slotsOut[(size_t)rg * 256 + c] = outv;
    }

    if (emit_qp) {
        __syncthreads();
        if (kh == 0) {
            float s1 = wred_sum(outv), s2 = wred_sum(outv * outv);
            if (lane == 0) { redA[wvi] = s1; redB[wvi] = s2; }
        }
        __syncthreads();
        if (kh == 0) {
            int base = rr * 4;
            float m  = (redA[base] + redA[base + 1] + redA[base + 2] + redA[base + 3]) * (1.f / 256.f);
            float e2 = (redB[base] + redB[base + 1] + redB[base + 2] + redB[base + 3]) * (1.f / 256.f);
            float rst = rsqrtf(e2 - m * m + LNEPS);
            M_s[rr][c] = (outv - m) * rst * ln_sl_g[c] + ln_sl_b[c];
        }
        __syncthreads();
        {
            int q2 = kh * 2 + rr;
            float p0 = 0.f, p1 = 0.f;
            const ushort_t* wp = Wqp + (size_t)c * 4;
            uint2 wreg[16];
#pragma unroll
            for (int i = 0; i < 16; i++) {
                int k4g = q2 * 16 + i;
                wreg[i] = *(const uint2*)(wp + (size_t)k4g * 1024);
            }
#pragma unroll
            for (int i = 0; i < 16; i++) {
                int k4g = q2 * 16 + i;
                float wA[4] = {bf2f(wreg[i].x & 0xffffu), bf2f(wreg[i].x >> 16),
                               bf2f(wreg[i].y & 0xffffu), bf2f(wreg[i].y >> 16)};
#pragma unroll
                for (int ii = 0; ii < 4; ii++) {
                    int k = k4g * 4 + ii;
                    p0 += M_s[0][k] * wA[ii];
                    p1 += M_s[1][k] * wA[ii];
                }
            }
            ppart[q2][0][c] = p0;
            ppart[q2][1][c] = p1;
        }
        __syncthreads();
        if (kh == 0) {
            float qv = ppart[0][rr][c] + ppart[1][rr][c] + ppart[2][rr][c] + ppart[3][rr][c];
            qp[(size_t)bb_ * 2048 + (c >> 6) * 512 + q * 64 + (c & 63)] = qv;
        }
    }
}

// -------- host --------
extern "C" void kernel_launch(void* const* d_in, const int* in_sizes, int n_in,
                              void* d_out, int out_size, void* d_ws, size_t ws_size,
                              hipStream_t stream) {
    const float* inputs   = (const float*)d_in[0];
    const float* slots0   = (const float*)d_in[1];
    const float* ln_in_g  = (const float*)d_in[2];
    const float* ln_in_b  = (const float*)d_in[3];
    const float* ln_sl_g  = (const float*)d_in[4];
    const float* ln_sl_b  = (const float*)d_in[5];
    const float* ln_mlp_g = (const float*)d_in[6];
    const float* ln_mlp_b = (const float*)d_in[7];
    const float* Wq       = (const float*)d_in[8];
    const float* Wk       = (const float*)d_in[9];
    const float* Wv       = (const float*)d_in[10];
    const float* w_ih     = (const float*)d_in[11];
    const float* w_hh     = (const float*)d_in[12];
    const float* b_ih     = (const float*)d_in[13];
    const float* b_hh     = (const float*)d_in[14];
    const float* w1       = (const float*)d_in[15];
    const float* b1       = (const float*)d_in[16];
    const float* w2       = (const float*)d_in[17];
    const float* b2       = (const float*)d_in[18];

    float* out_slots = (float*)d_out;
    float* out_vis   = (float*)d_out + 64 * 8 * 256;

    char* p = (char*)d_ws;
    auto carve = [&](size_t bytes) {
        void* r = (void*)p;
        p += (bytes + 255) & ~(size_t)255;
        return r;
    };
    ushort_t* kv   = (ushort_t*)carve((size_t)65536 * 512 * 2);   // 64 MB
    ushort_t* Wt   = (ushort_t*)carve((size_t)512 * 256 * 2);
    ushort_t* Wtp  = (ushort_t*)carve((size_t)512 * 256 * 2);
    ushort_t* wg   = (ushort_t*)carve((size_t)256 * 512 * 4 * 2);
    ushort_t* w1p  = (ushort_t*)carve((size_t)64 * 512 * 4 * 2);
    ushort_t* w2q  = (ushort_t*)carve((size_t)128 * 256 * 4 * 2);
    ushort_t* Wqp  = (ushort_t*)carve((size_t)64 * 256 * 4 * 2);
    float* qp      = (float*)carve((size_t)64 * 2048 * 4);
    float* Upart   = (float*)carve((size_t)64 * 8 * 2048 * 4);    // 4 MB
    float* Cpart   = (float*)carve((size_t)64 * 8 * 32 * 4);
    float* slotsA  = (float*)carve((size_t)512 * 256 * 4);

    prepack_w_kernel<<<512, 256, 0, stream>>>(Wk, Wv, Wt);
    prepack_wtp_kernel<<<64, 256, 0, stream>>>(Wt, Wtp);
    prepack_slotw_kernel<<<dim3(256, 4), 512, 0, stream>>>(w_ih, w_hh, w1, w2, Wq,
                                                           wg, w1p, w2q, Wqp);
    kvproj_mfma_kernel<<<1024, 512, 0, stream>>>(inputs, ln_in_g, ln_in_b, Wtp, kv);
    qproj_kernel<<<512, 256, 0, stream>>>(slots0, ln_sl_g, ln_sl_b, Wq, qp);

    for (int it = 0; it < 3; ++it) {
        attn_fused_kernel<<<dim3(8, 64), 256, 0, stream>>>(kv, qp, Upart, Cpart, out_vis,
                                                           (it == 2) ? 1 : 0);
        slot_fused_kernel<<<256, 1024, 0, stream>>>(
            Upart, Cpart, (it == 0) ? slots0 : slotsA,
            wg, b_ih, b_hh, ln_mlp_g, ln_mlp_b, w1p, b1, w2q, b2,
            ln_sl_g, ln_sl_b, Wqp,
            (it == 2) ? out_slots : slotsA, qp, (it < 2) ? 1 : 0);
    }
}